// Round 12
// baseline (615.986 us; speedup 1.0000x reference)
//
#include <hip/hip_runtime.h>
#include <stdint.h>

#define NTOK 16384
#define HD   1024
#define SD   256
#define NE   8

typedef short bf16x8 __attribute__((ext_vector_type(8)));
typedef _Float16 f16x8 __attribute__((ext_vector_type(8)));
typedef float f32x4 __attribute__((ext_vector_type(4)));
typedef unsigned short u16;
typedef unsigned short u16x8 __attribute__((ext_vector_type(8)));

__device__ __forceinline__ u16 f2bf(float f) {
  union { float f; unsigned u; } v; v.f = f;
  return (u16)((v.u + 0x7fffu + ((v.u >> 16) & 1u)) >> 16);
}

__device__ __forceinline__ void gload16(const void* g, void* l) {
  __builtin_amdgcn_global_load_lds((const __attribute__((address_space(1))) void*)g,
                                   (__attribute__((address_space(3))) void*)l,
                                   16, 0, 0);
}

// meta layout (ints): [0..7] counts, [8..15] cursors, [16..24] offsets,
// [25] ntiles, [27] rgemm-group-done counter, [32..191] tile_e,
// [192..351] tile_row0, [352..511] tile_end, [512..639] per-rowgroup counters

// LDS chunk-XOR swizzle (all GEMMs): conflict-free ds_read_b128 with unchanged
// VMEM coalescing (verified: conflicts 8.7M -> 0). K-loops fully unrolled (r8).
// r11: LDS-staged epilogues -> full-line stores (gemm1 WRITE 137->~68MB, -26us).
// r12: same epilogue for gemm2 (f32, 2 half-passes); logits fused into rgemm
// via last-tile-done (4 jt blocks of a row-group are same-XCD by swizzle
// construction -> L2-coherent hidden reads; 512 end-of-block atomics on 128
// distinct counters -- NOT the r9 per-token chained-atomic anti-pattern).
// r10 LESSON: keep rgemm grid 512 (2 blocks/CU); grid 256 = 1/CU lost TLP.

// ---------------- Fused prep: aprep (8192 blk) + bprep (64 blk) + tconv (4608 blk) ----------------
__global__ __launch_bounds__(256) void prep_kernel(
    const float* __restrict__ ue, _Float16* __restrict__ aP,
    const float* __restrict__ sw1, _Float16* __restrict__ bP,
    const float* __restrict__ ew1, const float* __restrict__ ew2,
    const float* __restrict__ uw1, const float* __restrict__ uw2,
    u16* __restrict__ ew1t, u16* __restrict__ ew2t,
    u16* __restrict__ uw1t, u16* __restrict__ uw2t) {
  const int bid = blockIdx.x;
  const int tid = threadIdx.x;
  if (bid < 8192) {
    // --- aprep: ue f32 -> A' = [hi | lo] fp16, row stride 2048 ---
    const int t = bid * 256 + tid;
    const int p = t >> 7;
    const int h = (t & 127) << 3;
    const float* s = ue + ((size_t)p << 10) + h;
    const float4 a = *(const float4*)s;
    const float4 b = *(const float4*)(s + 4);
    float v[8] = {a.x, a.y, a.z, a.w, b.x, b.y, b.z, b.w};
    f16x8 hi, lo;
#pragma unroll
    for (int j = 0; j < 8; ++j) {
      const _Float16 h16 = (_Float16)v[j];
      hi[j] = h16;
      lo[j] = (_Float16)(v[j] - (float)h16);
    }
    _Float16* d = aP + ((size_t)p << 11) + h;
    *(f16x8*)d = hi;
    *(f16x8*)(d + 1024) = lo;
    return;
  }
  __shared__ float tb[64][65];
  if (bid < 8256) {
    // --- bprep: sw1 [1024][256] f32 -> B' [256][3072] fp16 = [hi|lo|hi] ---
    const int b = bid - 8192;
    const int c0 = (b & 3) << 6;
    const int r0 = (b >> 2) << 6;
    {
      const int lr = tid >> 2, q = (tid & 3) << 4;
      const float* s = sw1 + (size_t)(r0 + lr) * SD + c0 + q;
#pragma unroll
      for (int j = 0; j < 16; j += 4) {
        const float4 v = *(const float4*)(s + j);
        tb[lr][q + j] = v.x; tb[lr][q + j + 1] = v.y;
        tb[lr][q + j + 2] = v.z; tb[lr][q + j + 3] = v.w;
      }
    }
    __syncthreads();
    const int lc = tid >> 2, rq = (tid & 3) << 4;
    f16x8 hi0, hi1, lo0, lo1;
#pragma unroll
    for (int j = 0; j < 8; ++j) {
      const float v0 = tb[rq + j][lc];
      const _Float16 h0 = (_Float16)v0;
      hi0[j] = h0; lo0[j] = (_Float16)(v0 - (float)h0);
      const float v1 = tb[rq + 8 + j][lc];
      const _Float16 h1 = (_Float16)v1;
      hi1[j] = h1; lo1[j] = (_Float16)(v1 - (float)h1);
    }
    _Float16* d = bP + (size_t)(c0 + lc) * 3072 + r0 + rq;
    *(f16x8*)d = hi0;           *(f16x8*)(d + 8) = hi1;
    *(f16x8*)(d + 1024) = lo0;  *(f16x8*)(d + 1032) = lo1;
    *(f16x8*)(d + 2048) = hi0;  *(f16x8*)(d + 2056) = hi1;
    return;
  }
  // --- tconv: transpose+convert 1024x1024 f32 -> bf16, 18 matrices ---
  const int c = bid - 8256;
  const int m = c >> 8;
  const int t2 = c & 255;
  const int c0 = (t2 & 15) << 6;
  const int r0 = (t2 >> 4) << 6;
  const size_t msz = (size_t)HD * HD;
  const float* src; u16* dst;
  if (m < 8)       { src = ew1 + (size_t)m * msz;       dst = ew1t + (size_t)m * msz; }
  else if (m < 16) { src = ew2 + (size_t)(m - 8) * msz; dst = ew2t + (size_t)(m - 8) * msz; }
  else if (m == 16){ src = uw1;                          dst = uw1t; }
  else             { src = uw2;                          dst = uw2t; }
  {
    const int lr = tid >> 2, q = (tid & 3) << 4;
    const float* s = src + (size_t)(r0 + lr) * HD + c0 + q;
#pragma unroll
    for (int j = 0; j < 16; j += 4) {
      const float4 v = *(const float4*)(s + j);
      tb[lr][q + j] = v.x; tb[lr][q + j + 1] = v.y;
      tb[lr][q + j + 2] = v.z; tb[lr][q + j + 3] = v.w;
    }
  }
  __syncthreads();
  {
    const int lc = tid >> 2, rq = (tid & 3) << 4;
    u16x8 o0, o1;
#pragma unroll
    for (int j = 0; j < 8; ++j) o0[j] = f2bf(tb[rq + j][lc]);
#pragma unroll
    for (int j = 0; j < 8; ++j) o1[j] = f2bf(tb[rq + 8 + j][lc]);
    u16* d = dst + (size_t)(c0 + lc) * HD + r0 + rq;
    *(u16x8*)d = o0;
    *(u16x8*)(d + 8) = o1;
  }
}

// ---------------- Router GEMM + fused logits/argmax/scan ----------------
__global__ __launch_bounds__(256) void rgemm_kernel(
    const _Float16* __restrict__ aP, const _Float16* __restrict__ bP,
    const float* __restrict__ sb1, float* __restrict__ hidden,
    const float* __restrict__ sw2, const float* __restrict__ sb2,
    int* __restrict__ routes, int* meta) {
  const int p = blockIdx.x;
  const int L = (p & 7) * 64 + (p >> 3);
  const int jt = L & 3;           // 64-col tile
  const int row0 = (L >> 2) << 7; // 128-row tile

  __shared__ _Float16 sA[2][128 * 32];
  __shared__ _Float16 sB[2][64 * 32];

  const int tid = threadIdx.x, lane = tid & 63, wave = tid >> 6;
  const int wr = (wave >> 1) << 6, wc = (wave & 1) << 5;
  const int smrow = tid >> 2, skoff = (((tid & 3) ^ ((tid >> 3) & 3)) << 3);
  const _Float16* ar0 = aP + ((size_t)(row0 + smrow) << 11) + skoff;
  const _Float16* ar1 = aP + ((size_t)(row0 + smrow + 64) << 11) + skoff;
  const _Float16* br  = bP + (size_t)((jt << 6) + smrow) * 3072 + skoff;
  const int ldsoff = wave << 10;

  f32x4 acc[4][2];
#pragma unroll
  for (int i = 0; i < 4; ++i)
#pragma unroll
    for (int j = 0; j < 2; ++j) acc[i][j] = (f32x4){0.f, 0.f, 0.f, 0.f};

  gload16(ar0, (char*)sA[0] + ldsoff);
  gload16(ar1, (char*)sA[0] + 4096 + ldsoff);
  gload16(br,  (char*)sB[0] + ldsoff);

  const int sl = (((lane >> 4) ^ ((lane >> 1) & 3)) << 3);
  const int afrag = (wr + (lane & 15)) * 32 + sl;
  const int bfrag = (wc + (lane & 15)) * 32 + sl;

#pragma unroll
  for (int ks = 0; ks < 96; ++ks) {
    const int buf = ks & 1;
    __syncthreads();
    if (ks + 1 < 96) {
      const int k1 = ks + 1;
      const int pa = (k1 < 64) ? ((k1 & 31) << 5) : (1024 + ((k1 - 64) << 5));
      gload16(ar0 + pa, (char*)sA[buf ^ 1] + ldsoff);
      gload16(ar1 + pa, (char*)sA[buf ^ 1] + 4096 + ldsoff);
      gload16(br + (k1 << 5), (char*)sB[buf ^ 1] + ldsoff);
    }
    f16x8 av[4], bv[2];
#pragma unroll
    for (int f = 0; f < 4; ++f) av[f] = *(const f16x8*)&sA[buf][afrag + f * 512];
#pragma unroll
    for (int f = 0; f < 2; ++f) bv[f] = *(const f16x8*)&sB[buf][bfrag + f * 512];
#pragma unroll
    for (int i = 0; i < 4; ++i)
#pragma unroll
      for (int j = 0; j < 2; ++j)
        acc[i][j] = __builtin_amdgcn_mfma_f32_16x16x32_f16(av[i], bv[j], acc[i][j], 0, 0, 0);
  }

  const int lc = lane & 15, lr4 = (lane >> 4) << 2;
#pragma unroll
  for (int j = 0; j < 2; ++j) {
    const int c = (jt << 6) + wc + (j << 4) + lc;
    const float bias = sb1[c];
#pragma unroll
    for (int i = 0; i < 4; ++i) {
      const int rl = wr + (i << 4) + lr4;
#pragma unroll
      for (int q = 0; q < 4; ++q)
        hidden[((size_t)(row0 + rl + q) << 8) + c] = fmaxf(acc[i][j][q] + bias, 0.f);
    }
  }

  // ---- last-of-4 jt blocks for this 128-row group runs logits+argmax ----
  // The 4 jt blocks are same-XCD by swizzle construction (L=4g..4g+3 within
  // one 64-block chunk) -> hidden reads hit the shared L2.
  __shared__ int isLast;
  __threadfence();
  if (tid == 0) isLast = (atomicAdd(&meta[512 + (row0 >> 7)], 1) == 3);
  __syncthreads();
  if (isLast == 0) return;

  __shared__ float logl[32][8];
  const int tl = tid >> 3, e2 = tid & 7;
#pragma unroll 1
  for (int g4 = 0; g4 < 4; ++g4) {
    const float* hp = hidden + ((size_t)(row0 + (g4 << 5) + tl) << 8);
    float a0 = 0.f, a1 = 0.f, a2 = 0.f, a3 = 0.f;
    for (int q = 0; q < SD; q += 8) {
      const float4 h0 = *(const float4*)&hp[q];
      const float4 h1 = *(const float4*)&hp[q + 4];
      a0 = fmaf(h0.x, sw2[((q + 0) << 3) + e2], a0);
      a1 = fmaf(h0.y, sw2[((q + 1) << 3) + e2], a1);
      a2 = fmaf(h0.z, sw2[((q + 2) << 3) + e2], a2);
      a3 = fmaf(h0.w, sw2[((q + 3) << 3) + e2], a3);
      a0 = fmaf(h1.x, sw2[((q + 4) << 3) + e2], a0);
      a1 = fmaf(h1.y, sw2[((q + 5) << 3) + e2], a1);
      a2 = fmaf(h1.z, sw2[((q + 6) << 3) + e2], a2);
      a3 = fmaf(h1.w, sw2[((q + 7) << 3) + e2], a3);
    }
    logl[tl][e2] = (a0 + a1) + (a2 + a3) + sb2[e2];
    __syncthreads();
    if (tid < 32) {
      float best = logl[tid][0]; int be = 0;
#pragma unroll
      for (int e = 1; e < 8; ++e) {
        const float v = logl[tid][e];
        if (v > best) { best = v; be = e; }
      }
      routes[row0 + (g4 << 5) + tid] = be;
      atomicAdd(&meta[be], 1);
    }
    __syncthreads();
  }
  // ---- last group overall runs the scan ----
  __threadfence();
  if (tid == 0) {
    const int done = atomicAdd(&meta[27], 1);
    if (done == 127) {
      int cnt[NE];
#pragma unroll
      for (int e = 0; e < NE; ++e) cnt[e] = atomicAdd(&meta[e], 0);
      int off = 0;
      for (int e = 0; e < NE; ++e) { meta[16 + e] = off; off += cnt[e]; }
      meta[24] = off;
      int nt = 0;
      for (int e = 0; e < NE; ++e) {
        const int s = meta[16 + e], en = meta[16 + e + 1];
        for (int r0 = s; r0 < en; r0 += 128) {
          meta[32 + nt] = e; meta[192 + nt] = r0; meta[352 + nt] = en; ++nt;
        }
      }
      meta[25] = nt;
      __threadfence();
    }
  }
}

// ---------------- Build permutation (token -> grouped position) ----------------
__global__ void perm_kernel(const int* __restrict__ routes, int* meta, int* __restrict__ perm) {
  const int b = blockIdx.x * 256 + threadIdx.x;
  const int r = routes[b];
  const int pos = meta[16 + r] + atomicAdd(&meta[8 + r], 1);
  perm[pos] = b;
}

// ---------------- Gather x rows into grouped order, f32 -> bf16 ----------------
__global__ __launch_bounds__(256) void gatherx_kernel(
    const float* __restrict__ x, const int* __restrict__ perm, u16* __restrict__ xg) {
  const int t = blockIdx.x * 256 + threadIdx.x;
  const int p = t >> 7;
  const int j = (t & 127) << 3;
  const int tok = perm[p];
  const float* s = &x[((size_t)tok << 10) + j];
  const float4 a = *(const float4*)s;
  const float4 b = *(const float4*)(s + 4);
  u16x8 o;
  o[0] = f2bf(a.x); o[1] = f2bf(a.y); o[2] = f2bf(a.z); o[3] = f2bf(a.w);
  o[4] = f2bf(b.x); o[5] = f2bf(b.y); o[6] = f2bf(b.z); o[7] = f2bf(b.w);
  *(u16x8*)&xg[((size_t)p << 10) + j] = o;
}

// ---------------- GEMM1: hid[p][0:2048] = relu(xg[p] @ [ew1[e] | uw1] + eb1[e]/ub1) ----------------
__global__ __launch_bounds__(256) void gemm1_kernel(
    const u16* __restrict__ xg, const u16* __restrict__ ew1t,
    const u16* __restrict__ uw1t, const float* __restrict__ eb1,
    const float* __restrict__ ub1, const int* __restrict__ meta,
    u16* __restrict__ hid) {
  const int nt = meta[25];
  // XCD-chunked, mt-major: grid 2160 = 16 jt x 135 mt
  const int pb = blockIdx.x;
  const int L = (pb & 7) * 270 + (pb >> 3);
  const int mt = L >> 4;
  const int jt = L & 15;
  if (mt >= nt) return;
  const int e = meta[32 + mt], row0 = meta[192 + mt], gend = meta[352 + mt];
  const u16* wbase = (jt < 8)
      ? ew1t + ((size_t)e << 20) + ((size_t)(jt << 7) << 10)
      : uw1t + ((size_t)((jt - 8) << 7) << 10);

  // 32KB unified LDS: K-loop sA/sB; epilogue reuses as [128][128] u16 tile.
  __shared__ u16 smem[16384];
  u16 (*sA)[4096] = (u16(*)[4096])smem;
  u16 (*sB)[4096] = (u16(*)[4096])(smem + 8192);

  const int tid = threadIdx.x;
  const int lane = tid & 63;
  const int wave = tid >> 6;
  const int wr = (wave >> 1) << 6;
  const int wc = (wave & 1) << 6;

  const int smrow = tid >> 2;
  const int skoff = (((tid & 3) ^ ((tid >> 3) & 3)) << 3);
  const u16* ap0 = xg + (((size_t)(row0 + smrow)) << 10) + skoff;
  const u16* ap1 = xg + (((size_t)(row0 + smrow + 64)) << 10) + skoff;
  const u16* bp0 = wbase + (((size_t)smrow) << 10) + skoff;
  const u16* bp1 = wbase + (((size_t)(smrow + 64)) << 10) + skoff;
  const int ldsoff = wave << 10;

  f32x4 acc[4][4];
#pragma unroll
  for (int i = 0; i < 4; ++i)
#pragma unroll
    for (int j = 0; j < 4; ++j) acc[i][j] = (f32x4){0.f, 0.f, 0.f, 0.f};

  gload16(ap0, (char*)sA[0] + ldsoff);
  gload16(ap1, (char*)sA[0] + 4096 + ldsoff);
  gload16(bp0, (char*)sB[0] + ldsoff);
  gload16(bp1, (char*)sB[0] + 4096 + ldsoff);

  const int sl = (((lane >> 4) ^ ((lane >> 1) & 3)) << 3);
  const int afrag = (wr + (lane & 15)) * 32 + sl;
  const int bfrag = (wc + (lane & 15)) * 32 + sl;

#pragma unroll
  for (int ks = 0; ks < 32; ++ks) {
    const int buf = ks & 1;
    __syncthreads();
    if (ks + 1 < 32) {
      const int k1 = (ks + 1) << 5;
      gload16(ap0 + k1, (char*)sA[buf ^ 1] + ldsoff);
      gload16(ap1 + k1, (char*)sA[buf ^ 1] + 4096 + ldsoff);
      gload16(bp0 + k1, (char*)sB[buf ^ 1] + ldsoff);
      gload16(bp1 + k1, (char*)sB[buf ^ 1] + 4096 + ldsoff);
    }
    bf16x8 av[4], bv[4];
#pragma unroll
    for (int f = 0; f < 4; ++f) {
      av[f] = *(const bf16x8*)&sA[buf][afrag + f * 512];
      bv[f] = *(const bf16x8*)&sB[buf][bfrag + f * 512];
    }
#pragma unroll
    for (int i = 0; i < 4; ++i)
#pragma unroll
      for (int j = 0; j < 4; ++j)
        acc[i][j] = __builtin_amdgcn_mfma_f32_16x16x32_bf16(av[i], bv[j], acc[i][j], 0, 0, 0);
  }

  // --- epilogue: bias+relu+cvt -> LDS tile, then 256B-contiguous stores ---
  __syncthreads();
  {
    const int lc = lane & 15;
    const int lr4 = (lane >> 4) << 2;
#pragma unroll
    for (int j = 0; j < 4; ++j) {
      const int c = wc + (j << 4) + lc;           // local col 0..127
      const int gc = (jt << 7) + c;
      const float bias = (gc < 1024) ? eb1[(e << 10) + gc] : ub1[gc - 1024];
#pragma unroll
      for (int i = 0; i < 4; ++i) {
        const int rl = wr + (i << 4) + lr4;
#pragma unroll
        for (int q = 0; q < 4; ++q)
          smem[(rl + q) * 128 + c] = f2bf(fmaxf(acc[i][j][q] + bias, 0.f));
      }
    }
  }
  __syncthreads();
  {
    const int l16 = lane & 15, rg = lane >> 4;
#pragma unroll
    for (int it = 0; it < 8; ++it) {
      const int lr = (wave << 5) + (it << 2) + rg;   // local row 0..127
      const int p = row0 + lr;
      const u16x8 v = *(const u16x8*)&smem[lr * 128 + (l16 << 3)];
      if (p < gend)
        *(u16x8*)&hid[((size_t)p << 11) + (jt << 7) + (l16 << 3)] = v;
    }
  }
}

// ---------------- GEMM2: out[perm[p]][c] = hid[p] @ [ew2[e]; uw2] + eb2[e] + ub2 ----------------
__global__ __launch_bounds__(256) void gemm2_kernel(
    const u16* __restrict__ hid, const u16* __restrict__ ew2t,
    const u16* __restrict__ uw2t, const float* __restrict__ eb2,
    const float* __restrict__ ub2, const int* __restrict__ meta,
    const int* __restrict__ perm, float* __restrict__ out) {
  const int nt = meta[25];
  // XCD-chunked, mt-major: grid 1080 = 8 jt x 135 mt
  const int pb = blockIdx.x;
  const int L = (pb & 7) * 135 + (pb >> 3);
  const int mt = L >> 3;
  const int jt = L & 7;
  if (mt >= nt) return;
  const int e = meta[32 + mt], row0 = meta[192 + mt], gend = meta[352 + mt];
  const int n0 = jt << 7;

  // 32KB unified LDS: K-loop sA/sB; epilogue reuses as [64][128] f32 half-tile.
  __shared__ u16 smem[16384];
  u16 (*sA)[4096] = (u16(*)[4096])smem;
  u16 (*sB)[4096] = (u16(*)[4096])(smem + 8192);
  float* smemf = (float*)smem;

  const int tid = threadIdx.x;
  const int lane = tid & 63;
  const int wave = tid >> 6;
  const int wr = (wave >> 1) << 6;
  const int wc = (wave & 1) << 6;

  const int smrow = tid >> 2;
  const int skoff = (((tid & 3) ^ ((tid >> 3) & 3)) << 3);
  const u16* ap0 = hid + (((size_t)(row0 + smrow)) << 11) + skoff;
  const u16* ap1 = hid + (((size_t)(row0 + smrow + 64)) << 11) + skoff;
  const u16* ebase = ew2t + ((size_t)e << 20);
  const size_t brow0 = (((size_t)(n0 + smrow)) << 10) + skoff;
  const size_t brow1 = (((size_t)(n0 + smrow + 64)) << 10) + skoff;
  const int ldsoff = wave << 10;

  f32x4 acc[4][4];
#pragma unroll
  for (int i = 0; i < 4; ++i)
#pragma unroll
    for (int j = 0; j < 4; ++j) acc[i][j] = (f32x4){0.f, 0.f, 0.f, 0.f};

  gload16(ap0, (char*)sA[0] + ldsoff);
  gload16(ap1, (char*)sA[0] + 4096 + ldsoff);
  gload16(ebase + brow0, (char*)sB[0] + ldsoff);
  gload16(ebase + brow1, (char*)sB[0] + 4096 + ldsoff);

  const int sl = (((lane >> 4) ^ ((lane >> 1) & 3)) << 3);
  const int afrag = (wr + (lane & 15)) * 32 + sl;
  const int bfrag = (wc + (lane & 15)) * 32 + sl;

#pragma unroll
  for (int ks = 0; ks < 64; ++ks) {
    const int buf = ks & 1;
    __syncthreads();
    if (ks + 1 < 64) {
      const int k1 = (ks + 1) << 5;
      const u16* bb = (k1 < 1024) ? ebase : uw2t;
      const int kk = k1 & 1023;
      gload16(ap0 + k1, (char*)sA[buf ^ 1] + ldsoff);
      gload16(ap1 + k1, (char*)sA[buf ^ 1] + 4096 + ldsoff);
      gload16(bb + brow0 + kk, (char*)sB[buf ^ 1] + ldsoff);
      gload16(bb + brow1 + kk, (char*)sB[buf ^ 1] + 4096 + ldsoff);
    }
    bf16x8 av[4], bv[4];
#pragma unroll
    for (int f = 0; f < 4; ++f) {
      av[f] = *(const bf16x8*)&sA[buf][afrag + f * 512];
      bv[f] = *(const bf16x8*)&sB[buf][bfrag + f * 512];
    }
#pragma unroll
    for (int i = 0; i < 4; ++i)
#pragma unroll
      for (int j = 0; j < 4; ++j)
        acc[i][j] = __builtin_amdgcn_mfma_f32_16x16x32_bf16(av[i], bv[j], acc[i][j], 0, 0, 0);
  }

  // --- epilogue: 2 half-passes via [64][128] f32 LDS tile, 512B/row stores ---
  const int lc = lane & 15;
  const int lr4 = (lane >> 4) << 2;
  float b2v[4];
#pragma unroll
  for (int j = 0; j < 4; ++j) {
    const int c = n0 + wc + (j << 4) + lc;
    b2v[j] = eb2[(e << 10) + c] + ub2[c];
  }
  __syncthreads();
#pragma unroll
  for (int pass = 0; pass < 2; ++pass) {
    if ((wave >> 1) == pass) {
#pragma unroll
      for (int j = 0; j < 4; ++j) {
        const int c = wc + (j << 4) + lc;         // local col 0..127
#pragma unroll
        for (int i = 0; i < 4; ++i) {
          const int lrl = (i << 4) + lr4;          // local row 0..63
#pragma unroll
          for (int q = 0; q < 4; ++q)
            smemf[(lrl + q) * 128 + c] = acc[i][j][q] + b2v[j];
        }
      }
    }
    __syncthreads();
#pragma unroll
    for (int it = 0; it < 8; ++it) {
      const int lrl = (it << 3) + (wave << 1) + (lane >> 5);  // 0..63
      const int p = row0 + (pass << 6) + lrl;
      const float4 v = *(const float4*)&smemf[lrl * 128 + ((lane & 31) << 2)];
      if (p < gend)
        *(float4*)&out[((size_t)perm[p] << 10) + n0 + ((lane & 31) << 2)] = v;
    }
    __syncthreads();
  }
}

extern "C" void kernel_launch(void* const* d_in, const int* in_sizes, int n_in,
                              void* d_out, int out_size, void* d_ws, size_t ws_size,
                              hipStream_t stream) {
  const float* x   = (const float*)d_in[0];
  const float* ue  = (const float*)d_in[1];
  const float* sw1 = (const float*)d_in[2];
  const float* sb1 = (const float*)d_in[3];
  const float* sw2 = (const float*)d_in[4];
  const float* sb2 = (const float*)d_in[5];
  const float* ew1 = (const float*)d_in[6];
  const float* eb1 = (const float*)d_in[7];
  const float* ew2 = (const float*)d_in[8];
  const float* eb2 = (const float*)d_in[9];
  const float* uw1 = (const float*)d_in[10];
  const float* ub1 = (const float*)d_in[11];
  const float* uw2 = (const float*)d_in[12];
  const float* ub2 = (const float*)d_in[13];
  float* out = (float*)d_out;

  char* w = (char*)d_ws;
  int* meta = (int*)w;    w += 4096;
  int* routes = (int*)w;  w += NTOK * 4;
  int* perm = (int*)w;    w += NTOK * 4;
  char* region = w;
  u16* xg   = (u16*)region;                                             // 33,816,576 B
  u16* ew1t = (u16*)(region + 33816576ull);                             // 16 MiB
  u16* ew2t = (u16*)(region + 33816576ull + 16777216ull);               // 16 MiB
  u16* uw1t = (u16*)(region + 33816576ull + 2 * 16777216ull);           // 2 MiB
  u16* uw2t = (u16*)(region + 33816576ull + 2 * 16777216ull + 2097152ull);
  u16* hid  = (u16*)(region + 33816576ull + 2 * 16777216ull + 2 * 2097152ull);  // 67,633,152 B
  const size_t region_sz = 33816576ull + 2 * 16777216ull + 2 * 2097152ull + 67633152ull;
  // router-phase aliases live in the (dead-until-gemm1) hid region / xg region:
  _Float16* aP     = (_Float16*)(region + 33816576ull + 2 * 16777216ull + 2 * 2097152ull);
  float* hidden32  = (float*)region;
  _Float16* bP     = (_Float16*)(region + 16777216ull);
  if (135168ull + region_sz > ws_size) return;

  hipMemsetAsync(meta, 0, 4096, stream);
  prep_kernel<<<12864, 256, 0, stream>>>(ue, aP, sw1, bP, ew1, ew2, uw1, uw2,
                                         ew1t, ew2t, uw1t, uw2t);
  rgemm_kernel<<<512, 256, 0, stream>>>(aP, bP, sb1, hidden32, sw2, sb2, routes, meta);
  perm_kernel<<<NTOK / 256, 256, 0, stream>>>(routes, meta, perm);
  gatherx_kernel<<<(NTOK * 128) / 256, 256, 0, stream>>>(x, perm, xg);
  gemm1_kernel<<<2160, 256, 0, stream>>>(xg, ew1t, uw1t, eb1, ub1, meta, hid);
  gemm2_kernel<<<1080, 256, 0, stream>>>(hid, ew2t, uw2t, eb2, ub2, meta, perm, out);
}

// Round 13
// 559.015 us; speedup vs baseline: 1.1019x; 1.1019x over previous
//
#include <hip/hip_runtime.h>
#include <stdint.h>

#define NTOK 16384
#define HD   1024
#define SD   256
#define NE   8

typedef short bf16x8 __attribute__((ext_vector_type(8)));
typedef _Float16 f16x8 __attribute__((ext_vector_type(8)));
typedef float f32x4 __attribute__((ext_vector_type(4)));
typedef unsigned short u16;
typedef unsigned short u16x8 __attribute__((ext_vector_type(8)));

__device__ __forceinline__ u16 f2bf(float f) {
  union { float f; unsigned u; } v; v.f = f;
  return (u16)((v.u + 0x7fffu + ((v.u >> 16) & 1u)) >> 16);
}

__device__ __forceinline__ void gload16(const void* g, void* l) {
  __builtin_amdgcn_global_load_lds((const __attribute__((address_space(1))) void*)g,
                                   (__attribute__((address_space(3))) void*)l,
                                   16, 0, 0);
}

// meta layout (ints): [0..7] counts, [8..15] cursors, [16..24] offsets,
// [25] ntiles, [26] logits-done counter, [32..191] tile_e, [192..351] tile_row0,
// [352..511] tile_end

// LDS chunk-XOR swizzle (all GEMMs): conflict-free ds_read_b128 with unchanged
// VMEM coalescing (verified: conflicts 8.7M -> 0). K-loops fully unrolled (r8).
// r11: LDS-staged epilogue gemm1 -> full-line stores (WRITE 137->~68MB, -26us).
// r12 LESSON: fusing logits into rgemm inflated its VGPR (64->100) + added a
// device fence -> occupancy collapse, rgemm 40->238us. Hot-kernel fusions that
// grow register/LDS footprint are NOT free. rgemm restored standalone.
// r10 LESSON: keep rgemm grid 512 (2 blocks/CU). r9 LESSON: no per-token
// atomic+barrier chains. gemm2 keeps the r12 LDS f32 epilogue (mechanism
// verified on gemm1).

// ---------------- Fused prep: aprep (8192 blk) + bprep (64 blk) + tconv (4608 blk) ----------------
__global__ __launch_bounds__(256) void prep_kernel(
    const float* __restrict__ ue, _Float16* __restrict__ aP,
    const float* __restrict__ sw1, _Float16* __restrict__ bP,
    const float* __restrict__ ew1, const float* __restrict__ ew2,
    const float* __restrict__ uw1, const float* __restrict__ uw2,
    u16* __restrict__ ew1t, u16* __restrict__ ew2t,
    u16* __restrict__ uw1t, u16* __restrict__ uw2t) {
  const int bid = blockIdx.x;
  const int tid = threadIdx.x;
  if (bid < 8192) {
    // --- aprep: ue f32 -> A' = [hi | lo] fp16, row stride 2048 ---
    const int t = bid * 256 + tid;
    const int p = t >> 7;
    const int h = (t & 127) << 3;
    const float* s = ue + ((size_t)p << 10) + h;
    const float4 a = *(const float4*)s;
    const float4 b = *(const float4*)(s + 4);
    float v[8] = {a.x, a.y, a.z, a.w, b.x, b.y, b.z, b.w};
    f16x8 hi, lo;
#pragma unroll
    for (int j = 0; j < 8; ++j) {
      const _Float16 h16 = (_Float16)v[j];
      hi[j] = h16;
      lo[j] = (_Float16)(v[j] - (float)h16);
    }
    _Float16* d = aP + ((size_t)p << 11) + h;
    *(f16x8*)d = hi;
    *(f16x8*)(d + 1024) = lo;
    return;
  }
  __shared__ float tb[64][65];
  if (bid < 8256) {
    // --- bprep: sw1 [1024][256] f32 -> B' [256][3072] fp16 = [hi|lo|hi] ---
    const int b = bid - 8192;
    const int c0 = (b & 3) << 6;
    const int r0 = (b >> 2) << 6;
    {
      const int lr = tid >> 2, q = (tid & 3) << 4;
      const float* s = sw1 + (size_t)(r0 + lr) * SD + c0 + q;
#pragma unroll
      for (int j = 0; j < 16; j += 4) {
        const float4 v = *(const float4*)(s + j);
        tb[lr][q + j] = v.x; tb[lr][q + j + 1] = v.y;
        tb[lr][q + j + 2] = v.z; tb[lr][q + j + 3] = v.w;
      }
    }
    __syncthreads();
    const int lc = tid >> 2, rq = (tid & 3) << 4;
    f16x8 hi0, hi1, lo0, lo1;
#pragma unroll
    for (int j = 0; j < 8; ++j) {
      const float v0 = tb[rq + j][lc];
      const _Float16 h0 = (_Float16)v0;
      hi0[j] = h0; lo0[j] = (_Float16)(v0 - (float)h0);
      const float v1 = tb[rq + 8 + j][lc];
      const _Float16 h1 = (_Float16)v1;
      hi1[j] = h1; lo1[j] = (_Float16)(v1 - (float)h1);
    }
    _Float16* d = bP + (size_t)(c0 + lc) * 3072 + r0 + rq;
    *(f16x8*)d = hi0;           *(f16x8*)(d + 8) = hi1;
    *(f16x8*)(d + 1024) = lo0;  *(f16x8*)(d + 1032) = lo1;
    *(f16x8*)(d + 2048) = hi0;  *(f16x8*)(d + 2056) = hi1;
    return;
  }
  // --- tconv: transpose+convert 1024x1024 f32 -> bf16, 18 matrices ---
  const int c = bid - 8256;
  const int m = c >> 8;
  const int t2 = c & 255;
  const int c0 = (t2 & 15) << 6;
  const int r0 = (t2 >> 4) << 6;
  const size_t msz = (size_t)HD * HD;
  const float* src; u16* dst;
  if (m < 8)       { src = ew1 + (size_t)m * msz;       dst = ew1t + (size_t)m * msz; }
  else if (m < 16) { src = ew2 + (size_t)(m - 8) * msz; dst = ew2t + (size_t)(m - 8) * msz; }
  else if (m == 16){ src = uw1;                          dst = uw1t; }
  else             { src = uw2;                          dst = uw2t; }
  {
    const int lr = tid >> 2, q = (tid & 3) << 4;
    const float* s = src + (size_t)(r0 + lr) * HD + c0 + q;
#pragma unroll
    for (int j = 0; j < 16; j += 4) {
      const float4 v = *(const float4*)(s + j);
      tb[lr][q + j] = v.x; tb[lr][q + j + 1] = v.y;
      tb[lr][q + j + 2] = v.z; tb[lr][q + j + 3] = v.w;
    }
  }
  __syncthreads();
  {
    const int lc = tid >> 2, rq = (tid & 3) << 4;
    u16x8 o0, o1;
#pragma unroll
    for (int j = 0; j < 8; ++j) o0[j] = f2bf(tb[rq + j][lc]);
#pragma unroll
    for (int j = 0; j < 8; ++j) o1[j] = f2bf(tb[rq + 8 + j][lc]);
    u16* d = dst + (size_t)(c0 + lc) * HD + r0 + rq;
    *(u16x8*)d = o0;
    *(u16x8*)(d + 8) = o1;
  }
}

// ---------------- Router GEMM: hidden[p][s] = relu(3-term hi/lo fp16 MFMA + sb1), f32 out ----------------
__global__ __launch_bounds__(256) void rgemm_kernel(
    const _Float16* __restrict__ aP, const _Float16* __restrict__ bP,
    const float* __restrict__ sb1, float* __restrict__ hidden) {
  const int p = blockIdx.x;
  const int L = (p & 7) * 64 + (p >> 3);
  const int jt = L & 3;           // 64-col tile
  const int row0 = (L >> 2) << 7; // 128-row tile

  __shared__ _Float16 sA[2][128 * 32];
  __shared__ _Float16 sB[2][64 * 32];

  const int tid = threadIdx.x, lane = tid & 63, wave = tid >> 6;
  const int wr = (wave >> 1) << 6, wc = (wave & 1) << 5;
  const int smrow = tid >> 2, skoff = (((tid & 3) ^ ((tid >> 3) & 3)) << 3);
  const _Float16* ar0 = aP + ((size_t)(row0 + smrow) << 11) + skoff;
  const _Float16* ar1 = aP + ((size_t)(row0 + smrow + 64) << 11) + skoff;
  const _Float16* br  = bP + (size_t)((jt << 6) + smrow) * 3072 + skoff;
  const int ldsoff = wave << 10;

  f32x4 acc[4][2];
#pragma unroll
  for (int i = 0; i < 4; ++i)
#pragma unroll
    for (int j = 0; j < 2; ++j) acc[i][j] = (f32x4){0.f, 0.f, 0.f, 0.f};

  gload16(ar0, (char*)sA[0] + ldsoff);
  gload16(ar1, (char*)sA[0] + 4096 + ldsoff);
  gload16(br,  (char*)sB[0] + ldsoff);

  const int sl = (((lane >> 4) ^ ((lane >> 1) & 3)) << 3);
  const int afrag = (wr + (lane & 15)) * 32 + sl;
  const int bfrag = (wc + (lane & 15)) * 32 + sl;

#pragma unroll
  for (int ks = 0; ks < 96; ++ks) {
    const int buf = ks & 1;
    __syncthreads();
    if (ks + 1 < 96) {
      const int k1 = ks + 1;
      const int pa = (k1 < 64) ? ((k1 & 31) << 5) : (1024 + ((k1 - 64) << 5));
      gload16(ar0 + pa, (char*)sA[buf ^ 1] + ldsoff);
      gload16(ar1 + pa, (char*)sA[buf ^ 1] + 4096 + ldsoff);
      gload16(br + (k1 << 5), (char*)sB[buf ^ 1] + ldsoff);
    }
    f16x8 av[4], bv[2];
#pragma unroll
    for (int f = 0; f < 4; ++f) av[f] = *(const f16x8*)&sA[buf][afrag + f * 512];
#pragma unroll
    for (int f = 0; f < 2; ++f) bv[f] = *(const f16x8*)&sB[buf][bfrag + f * 512];
#pragma unroll
    for (int i = 0; i < 4; ++i)
#pragma unroll
      for (int j = 0; j < 2; ++j)
        acc[i][j] = __builtin_amdgcn_mfma_f32_16x16x32_f16(av[i], bv[j], acc[i][j], 0, 0, 0);
  }

  const int lc = lane & 15, lr4 = (lane >> 4) << 2;
#pragma unroll
  for (int j = 0; j < 2; ++j) {
    const int c = (jt << 6) + wc + (j << 4) + lc;
    const float bias = sb1[c];
#pragma unroll
    for (int i = 0; i < 4; ++i) {
      const int rl = wr + (i << 4) + lr4;
#pragma unroll
      for (int q = 0; q < 4; ++q)
        hidden[((size_t)(row0 + rl + q) << 8) + c] = fmaxf(acc[i][j][q] + bias, 0.f);
    }
  }
}

// ---------------- Logits layer-2 + argmax + histogram + fused scan (last block) ----------------
__global__ __launch_bounds__(256) void logits_kernel(
    const float* __restrict__ hidden, const float* __restrict__ sw2,
    const float* __restrict__ sb2, int* __restrict__ routes, int* meta) {
  __shared__ float logl[32][8];
  const int tid = threadIdx.x;
  const int tok0 = blockIdx.x << 5;
  const int tl = tid >> 3, e2 = tid & 7;
  const float* hp = hidden + ((size_t)(tok0 + tl) << 8);
  float a0 = 0.f, a1 = 0.f, a2 = 0.f, a3 = 0.f;
  for (int q = 0; q < SD; q += 8) {
    const float4 h0 = *(const float4*)&hp[q];
    const float4 h1 = *(const float4*)&hp[q + 4];
    a0 = fmaf(h0.x, sw2[((q + 0) << 3) + e2], a0);
    a1 = fmaf(h0.y, sw2[((q + 1) << 3) + e2], a1);
    a2 = fmaf(h0.z, sw2[((q + 2) << 3) + e2], a2);
    a3 = fmaf(h0.w, sw2[((q + 3) << 3) + e2], a3);
    a0 = fmaf(h1.x, sw2[((q + 4) << 3) + e2], a0);
    a1 = fmaf(h1.y, sw2[((q + 5) << 3) + e2], a1);
    a2 = fmaf(h1.z, sw2[((q + 6) << 3) + e2], a2);
    a3 = fmaf(h1.w, sw2[((q + 7) << 3) + e2], a3);
  }
  logl[tl][e2] = (a0 + a1) + (a2 + a3) + sb2[e2];
  __syncthreads();
  if (tid < 32) {
    float best = logl[tid][0]; int be = 0;
#pragma unroll
    for (int e = 1; e < 8; ++e) {
      const float v = logl[tid][e];
      if (v > best) { best = v; be = e; }
    }
    routes[tok0 + tid] = be;
    atomicAdd(&meta[be], 1);
  }
  // last-block-done: fused scan (replaces scan_kernel launch)
  __syncthreads();
  if (tid == 0) {
    __threadfence();
    const int done = atomicAdd(&meta[26], 1);
    if (done == (int)gridDim.x - 1) {
      int cnt[NE];
#pragma unroll
      for (int e = 0; e < NE; ++e) cnt[e] = atomicAdd(&meta[e], 0);
      int off = 0;
      for (int e = 0; e < NE; ++e) { meta[16 + e] = off; off += cnt[e]; }
      meta[24] = off;
      int nt = 0;
      for (int e = 0; e < NE; ++e) {
        const int s = meta[16 + e], en = meta[16 + e + 1];
        for (int r0 = s; r0 < en; r0 += 128) {
          meta[32 + nt] = e; meta[192 + nt] = r0; meta[352 + nt] = en; ++nt;
        }
      }
      meta[25] = nt;
      __threadfence();
    }
  }
}

// ---------------- Build permutation (token -> grouped position) ----------------
__global__ void perm_kernel(const int* __restrict__ routes, int* meta, int* __restrict__ perm) {
  const int b = blockIdx.x * 256 + threadIdx.x;
  const int r = routes[b];
  const int pos = meta[16 + r] + atomicAdd(&meta[8 + r], 1);
  perm[pos] = b;
}

// ---------------- Gather x rows into grouped order, f32 -> bf16 ----------------
__global__ __launch_bounds__(256) void gatherx_kernel(
    const float* __restrict__ x, const int* __restrict__ perm, u16* __restrict__ xg) {
  const int t = blockIdx.x * 256 + threadIdx.x;
  const int p = t >> 7;
  const int j = (t & 127) << 3;
  const int tok = perm[p];
  const float* s = &x[((size_t)tok << 10) + j];
  const float4 a = *(const float4*)s;
  const float4 b = *(const float4*)(s + 4);
  u16x8 o;
  o[0] = f2bf(a.x); o[1] = f2bf(a.y); o[2] = f2bf(a.z); o[3] = f2bf(a.w);
  o[4] = f2bf(b.x); o[5] = f2bf(b.y); o[6] = f2bf(b.z); o[7] = f2bf(b.w);
  *(u16x8*)&xg[((size_t)p << 10) + j] = o;
}

// ---------------- GEMM1: hid[p][0:2048] = relu(xg[p] @ [ew1[e] | uw1] + eb1[e]/ub1) ----------------
__global__ __launch_bounds__(256) void gemm1_kernel(
    const u16* __restrict__ xg, const u16* __restrict__ ew1t,
    const u16* __restrict__ uw1t, const float* __restrict__ eb1,
    const float* __restrict__ ub1, const int* __restrict__ meta,
    u16* __restrict__ hid) {
  const int nt = meta[25];
  // XCD-chunked, mt-major: grid 2160 = 16 jt x 135 mt
  const int pb = blockIdx.x;
  const int L = (pb & 7) * 270 + (pb >> 3);
  const int mt = L >> 4;
  const int jt = L & 15;
  if (mt >= nt) return;
  const int e = meta[32 + mt], row0 = meta[192 + mt], gend = meta[352 + mt];
  const u16* wbase = (jt < 8)
      ? ew1t + ((size_t)e << 20) + ((size_t)(jt << 7) << 10)
      : uw1t + ((size_t)((jt - 8) << 7) << 10);

  // 32KB unified LDS: K-loop sA/sB; epilogue reuses as [128][128] u16 tile.
  __shared__ u16 smem[16384];
  u16 (*sA)[4096] = (u16(*)[4096])smem;
  u16 (*sB)[4096] = (u16(*)[4096])(smem + 8192);

  const int tid = threadIdx.x;
  const int lane = tid & 63;
  const int wave = tid >> 6;
  const int wr = (wave >> 1) << 6;
  const int wc = (wave & 1) << 6;

  const int smrow = tid >> 2;
  const int skoff = (((tid & 3) ^ ((tid >> 3) & 3)) << 3);
  const u16* ap0 = xg + (((size_t)(row0 + smrow)) << 10) + skoff;
  const u16* ap1 = xg + (((size_t)(row0 + smrow + 64)) << 10) + skoff;
  const u16* bp0 = wbase + (((size_t)smrow) << 10) + skoff;
  const u16* bp1 = wbase + (((size_t)(smrow + 64)) << 10) + skoff;
  const int ldsoff = wave << 10;

  f32x4 acc[4][4];
#pragma unroll
  for (int i = 0; i < 4; ++i)
#pragma unroll
    for (int j = 0; j < 4; ++j) acc[i][j] = (f32x4){0.f, 0.f, 0.f, 0.f};

  gload16(ap0, (char*)sA[0] + ldsoff);
  gload16(ap1, (char*)sA[0] + 4096 + ldsoff);
  gload16(bp0, (char*)sB[0] + ldsoff);
  gload16(bp1, (char*)sB[0] + 4096 + ldsoff);

  const int sl = (((lane >> 4) ^ ((lane >> 1) & 3)) << 3);
  const int afrag = (wr + (lane & 15)) * 32 + sl;
  const int bfrag = (wc + (lane & 15)) * 32 + sl;

#pragma unroll
  for (int ks = 0; ks < 32; ++ks) {
    const int buf = ks & 1;
    __syncthreads();
    if (ks + 1 < 32) {
      const int k1 = (ks + 1) << 5;
      gload16(ap0 + k1, (char*)sA[buf ^ 1] + ldsoff);
      gload16(ap1 + k1, (char*)sA[buf ^ 1] + 4096 + ldsoff);
      gload16(bp0 + k1, (char*)sB[buf ^ 1] + ldsoff);
      gload16(bp1 + k1, (char*)sB[buf ^ 1] + 4096 + ldsoff);
    }
    bf16x8 av[4], bv[4];
#pragma unroll
    for (int f = 0; f < 4; ++f) {
      av[f] = *(const bf16x8*)&sA[buf][afrag + f * 512];
      bv[f] = *(const bf16x8*)&sB[buf][bfrag + f * 512];
    }
#pragma unroll
    for (int i = 0; i < 4; ++i)
#pragma unroll
      for (int j = 0; j < 4; ++j)
        acc[i][j] = __builtin_amdgcn_mfma_f32_16x16x32_bf16(av[i], bv[j], acc[i][j], 0, 0, 0);
  }

  // --- epilogue: bias+relu+cvt -> LDS tile, then 256B-contiguous stores ---
  __syncthreads();
  {
    const int lc = lane & 15;
    const int lr4 = (lane >> 4) << 2;
#pragma unroll
    for (int j = 0; j < 4; ++j) {
      const int c = wc + (j << 4) + lc;           // local col 0..127
      const int gc = (jt << 7) + c;
      const float bias = (gc < 1024) ? eb1[(e << 10) + gc] : ub1[gc - 1024];
#pragma unroll
      for (int i = 0; i < 4; ++i) {
        const int rl = wr + (i << 4) + lr4;
#pragma unroll
        for (int q = 0; q < 4; ++q)
          smem[(rl + q) * 128 + c] = f2bf(fmaxf(acc[i][j][q] + bias, 0.f));
      }
    }
  }
  __syncthreads();
  {
    const int l16 = lane & 15, rg = lane >> 4;
#pragma unroll
    for (int it = 0; it < 8; ++it) {
      const int lr = (wave << 5) + (it << 2) + rg;   // local row 0..127
      const int p = row0 + lr;
      const u16x8 v = *(const u16x8*)&smem[lr * 128 + (l16 << 3)];
      if (p < gend)
        *(u16x8*)&hid[((size_t)p << 11) + (jt << 7) + (l16 << 3)] = v;
    }
  }
}

// ---------------- GEMM2: out[perm[p]][c] = hid[p] @ [ew2[e]; uw2] + eb2[e] + ub2 ----------------
__global__ __launch_bounds__(256) void gemm2_kernel(
    const u16* __restrict__ hid, const u16* __restrict__ ew2t,
    const u16* __restrict__ uw2t, const float* __restrict__ eb2,
    const float* __restrict__ ub2, const int* __restrict__ meta,
    const int* __restrict__ perm, float* __restrict__ out) {
  const int nt = meta[25];
  // XCD-chunked, mt-major: grid 1080 = 8 jt x 135 mt
  const int pb = blockIdx.x;
  const int L = (pb & 7) * 135 + (pb >> 3);
  const int mt = L >> 3;
  const int jt = L & 7;
  if (mt >= nt) return;
  const int e = meta[32 + mt], row0 = meta[192 + mt], gend = meta[352 + mt];
  const int n0 = jt << 7;

  // 32KB unified LDS: K-loop sA/sB; epilogue reuses as [64][128] f32 half-tile.
  __shared__ u16 smem[16384];
  u16 (*sA)[4096] = (u16(*)[4096])smem;
  u16 (*sB)[4096] = (u16(*)[4096])(smem + 8192);
  float* smemf = (float*)smem;

  const int tid = threadIdx.x;
  const int lane = tid & 63;
  const int wave = tid >> 6;
  const int wr = (wave >> 1) << 6;
  const int wc = (wave & 1) << 6;

  const int smrow = tid >> 2;
  const int skoff = (((tid & 3) ^ ((tid >> 3) & 3)) << 3);
  const u16* ap0 = hid + (((size_t)(row0 + smrow)) << 11) + skoff;
  const u16* ap1 = hid + (((size_t)(row0 + smrow + 64)) << 11) + skoff;
  const u16* ebase = ew2t + ((size_t)e << 20);
  const size_t brow0 = (((size_t)(n0 + smrow)) << 10) + skoff;
  const size_t brow1 = (((size_t)(n0 + smrow + 64)) << 10) + skoff;
  const int ldsoff = wave << 10;

  f32x4 acc[4][4];
#pragma unroll
  for (int i = 0; i < 4; ++i)
#pragma unroll
    for (int j = 0; j < 4; ++j) acc[i][j] = (f32x4){0.f, 0.f, 0.f, 0.f};

  gload16(ap0, (char*)sA[0] + ldsoff);
  gload16(ap1, (char*)sA[0] + 4096 + ldsoff);
  gload16(ebase + brow0, (char*)sB[0] + ldsoff);
  gload16(ebase + brow1, (char*)sB[0] + 4096 + ldsoff);

  const int sl = (((lane >> 4) ^ ((lane >> 1) & 3)) << 3);
  const int afrag = (wr + (lane & 15)) * 32 + sl;
  const int bfrag = (wc + (lane & 15)) * 32 + sl;

#pragma unroll
  for (int ks = 0; ks < 64; ++ks) {
    const int buf = ks & 1;
    __syncthreads();
    if (ks + 1 < 64) {
      const int k1 = (ks + 1) << 5;
      const u16* bb = (k1 < 1024) ? ebase : uw2t;
      const int kk = k1 & 1023;
      gload16(ap0 + k1, (char*)sA[buf ^ 1] + ldsoff);
      gload16(ap1 + k1, (char*)sA[buf ^ 1] + 4096 + ldsoff);
      gload16(bb + brow0 + kk, (char*)sB[buf ^ 1] + ldsoff);
      gload16(bb + brow1 + kk, (char*)sB[buf ^ 1] + 4096 + ldsoff);
    }
    bf16x8 av[4], bv[4];
#pragma unroll
    for (int f = 0; f < 4; ++f) {
      av[f] = *(const bf16x8*)&sA[buf][afrag + f * 512];
      bv[f] = *(const bf16x8*)&sB[buf][bfrag + f * 512];
    }
#pragma unroll
    for (int i = 0; i < 4; ++i)
#pragma unroll
      for (int j = 0; j < 4; ++j)
        acc[i][j] = __builtin_amdgcn_mfma_f32_16x16x32_bf16(av[i], bv[j], acc[i][j], 0, 0, 0);
  }

  // --- epilogue: 2 half-passes via [64][128] f32 LDS tile, 512B/row stores ---
  const int lc = lane & 15;
  const int lr4 = (lane >> 4) << 2;
  float b2v[4];
#pragma unroll
  for (int j = 0; j < 4; ++j) {
    const int c = n0 + wc + (j << 4) + lc;
    b2v[j] = eb2[(e << 10) + c] + ub2[c];
  }
  __syncthreads();
#pragma unroll
  for (int pass = 0; pass < 2; ++pass) {
    if ((wave >> 1) == pass) {
#pragma unroll
      for (int j = 0; j < 4; ++j) {
        const int c = wc + (j << 4) + lc;         // local col 0..127
#pragma unroll
        for (int i = 0; i < 4; ++i) {
          const int lrl = (i << 4) + lr4;          // local row 0..63
#pragma unroll
          for (int q = 0; q < 4; ++q)
            smemf[(lrl + q) * 128 + c] = acc[i][j][q] + b2v[j];
        }
      }
    }
    __syncthreads();
#pragma unroll
    for (int it = 0; it < 8; ++it) {
      const int lrl = (it << 3) + (wave << 1) + (lane >> 5);  // 0..63
      const int p = row0 + (pass << 6) + lrl;
      const float4 v = *(const float4*)&smemf[lrl * 128 + ((lane & 31) << 2)];
      if (p < gend)
        *(float4*)&out[((size_t)perm[p] << 10) + n0 + ((lane & 31) << 2)] = v;
    }
    __syncthreads();
  }
}

extern "C" void kernel_launch(void* const* d_in, const int* in_sizes, int n_in,
                              void* d_out, int out_size, void* d_ws, size_t ws_size,
                              hipStream_t stream) {
  const float* x   = (const float*)d_in[0];
  const float* ue  = (const float*)d_in[1];
  const float* sw1 = (const float*)d_in[2];
  const float* sb1 = (const float*)d_in[3];
  const float* sw2 = (const float*)d_in[4];
  const float* sb2 = (const float*)d_in[5];
  const float* ew1 = (const float*)d_in[6];
  const float* eb1 = (const float*)d_in[7];
  const float* ew2 = (const float*)d_in[8];
  const float* eb2 = (const float*)d_in[9];
  const float* uw1 = (const float*)d_in[10];
  const float* ub1 = (const float*)d_in[11];
  const float* uw2 = (const float*)d_in[12];
  const float* ub2 = (const float*)d_in[13];
  float* out = (float*)d_out;

  char* w = (char*)d_ws;
  int* meta = (int*)w;    w += 4096;
  int* routes = (int*)w;  w += NTOK * 4;
  int* perm = (int*)w;    w += NTOK * 4;
  char* region = w;
  u16* xg   = (u16*)region;                                             // 33,816,576 B
  u16* ew1t = (u16*)(region + 33816576ull);                             // 16 MiB
  u16* ew2t = (u16*)(region + 33816576ull + 16777216ull);               // 16 MiB
  u16* uw1t = (u16*)(region + 33816576ull + 2 * 16777216ull);           // 2 MiB
  u16* uw2t = (u16*)(region + 33816576ull + 2 * 16777216ull + 2097152ull);
  u16* hid  = (u16*)(region + 33816576ull + 2 * 16777216ull + 2 * 2097152ull);  // 67,633,152 B
  const size_t region_sz = 33816576ull + 2 * 16777216ull + 2 * 2097152ull + 67633152ull;
  // router-phase aliases live in the (dead-until-gemm1) hid region / xg region:
  _Float16* aP     = (_Float16*)(region + 33816576ull + 2 * 16777216ull + 2 * 2097152ull);
  float* hidden32  = (float*)region;
  _Float16* bP     = (_Float16*)(region + 16777216ull);
  if (135168ull + region_sz > ws_size) return;

  hipMemsetAsync(meta, 0, 4096, stream);
  prep_kernel<<<12864, 256, 0, stream>>>(ue, aP, sw1, bP, ew1, ew2, uw1, uw2,
                                         ew1t, ew2t, uw1t, uw2t);
  rgemm_kernel<<<512, 256, 0, stream>>>(aP, bP, sb1, hidden32);
  logits_kernel<<<NTOK / 32, 256, 0, stream>>>(hidden32, sw2, sb2, routes, meta);
  perm_kernel<<<NTOK / 256, 256, 0, stream>>>(routes, meta, perm);
  gatherx_kernel<<<(NTOK * 128) / 256, 256, 0, stream>>>(x, perm, xg);
  gemm1_kernel<<<2160, 256, 0, stream>>>(xg, ew1t, uw1t, eb1, ub1, meta, hid);
  gemm2_kernel<<<1080, 256, 0, stream>>>(hid, ew2t, uw2t, eb2, ub2, meta, perm, out);
}

// Round 14
// 441.687 us; speedup vs baseline: 1.3946x; 1.2656x over previous
//
#include <hip/hip_runtime.h>
#include <stdint.h>

#define NTOK 16384
#define HD   1024
#define SD   256
#define NE   8

typedef short bf16x8 __attribute__((ext_vector_type(8)));
typedef _Float16 f16x8 __attribute__((ext_vector_type(8)));
typedef float f32x4 __attribute__((ext_vector_type(4)));
typedef unsigned short u16;
typedef unsigned short u16x8 __attribute__((ext_vector_type(8)));

__device__ __forceinline__ u16 f2bf(float f) {
  union { float f; unsigned u; } v; v.f = f;
  return (u16)((v.u + 0x7fffu + ((v.u >> 16) & 1u)) >> 16);
}

__device__ __forceinline__ void gload16(const void* g, void* l) {
  __builtin_amdgcn_global_load_lds((const __attribute__((address_space(1))) void*)g,
                                   (__attribute__((address_space(3))) void*)l,
                                   16, 0, 0);
}

// meta layout (ints): [0..7] counts, [8..15] cursors, [16..24] offsets,
// [25] ntiles, [26] logits-done counter, [32..191] tile_e, [192..351] tile_row0,
// [352..511] tile_end

// LDS chunk-XOR swizzle (all GEMMs): conflict-free ds_read_b128 with unchanged
// VMEM coalescing (verified: conflicts 8.7M -> 0). K-loops fully unrolled (r8).
// r11/r12: LDS-staged epilogues -> full-line stores (gemm1+gemm2, -50us total).
// r13 FINDING: standalone perm_kernel was a hidden 127us serial chain -- 16384
// atomics on ONE cache line (8 cursors x 4B) bouncing across XCDs at ~8ns each.
// Fix: two-level counting (LDS histogram -> 8 global atomics/block -> LDS
// ranks). Intra-expert order changes; correctness only needs grouping-by-expert
// (gemm2 writes through perm[p]).
// r12 LESSON: don't fuse work into hot GEMMs if it grows VGPR/LDS (occupancy).
// r10 LESSON: rgemm grid 512 (2 blocks/CU). r9 LESSON: no atomic+barrier chains.

// ---------------- Fused prep: aprep (8192 blk) + bprep (64 blk) + tconv (4608 blk) ----------------
__global__ __launch_bounds__(256) void prep_kernel(
    const float* __restrict__ ue, _Float16* __restrict__ aP,
    const float* __restrict__ sw1, _Float16* __restrict__ bP,
    const float* __restrict__ ew1, const float* __restrict__ ew2,
    const float* __restrict__ uw1, const float* __restrict__ uw2,
    u16* __restrict__ ew1t, u16* __restrict__ ew2t,
    u16* __restrict__ uw1t, u16* __restrict__ uw2t) {
  const int bid = blockIdx.x;
  const int tid = threadIdx.x;
  if (bid < 8192) {
    // --- aprep: ue f32 -> A' = [hi | lo] fp16, row stride 2048 ---
    const int t = bid * 256 + tid;
    const int p = t >> 7;
    const int h = (t & 127) << 3;
    const float* s = ue + ((size_t)p << 10) + h;
    const float4 a = *(const float4*)s;
    const float4 b = *(const float4*)(s + 4);
    float v[8] = {a.x, a.y, a.z, a.w, b.x, b.y, b.z, b.w};
    f16x8 hi, lo;
#pragma unroll
    for (int j = 0; j < 8; ++j) {
      const _Float16 h16 = (_Float16)v[j];
      hi[j] = h16;
      lo[j] = (_Float16)(v[j] - (float)h16);
    }
    _Float16* d = aP + ((size_t)p << 11) + h;
    *(f16x8*)d = hi;
    *(f16x8*)(d + 1024) = lo;
    return;
  }
  __shared__ float tb[64][65];
  if (bid < 8256) {
    // --- bprep: sw1 [1024][256] f32 -> B' [256][3072] fp16 = [hi|lo|hi] ---
    const int b = bid - 8192;
    const int c0 = (b & 3) << 6;
    const int r0 = (b >> 2) << 6;
    {
      const int lr = tid >> 2, q = (tid & 3) << 4;
      const float* s = sw1 + (size_t)(r0 + lr) * SD + c0 + q;
#pragma unroll
      for (int j = 0; j < 16; j += 4) {
        const float4 v = *(const float4*)(s + j);
        tb[lr][q + j] = v.x; tb[lr][q + j + 1] = v.y;
        tb[lr][q + j + 2] = v.z; tb[lr][q + j + 3] = v.w;
      }
    }
    __syncthreads();
    const int lc = tid >> 2, rq = (tid & 3) << 4;
    f16x8 hi0, hi1, lo0, lo1;
#pragma unroll
    for (int j = 0; j < 8; ++j) {
      const float v0 = tb[rq + j][lc];
      const _Float16 h0 = (_Float16)v0;
      hi0[j] = h0; lo0[j] = (_Float16)(v0 - (float)h0);
      const float v1 = tb[rq + 8 + j][lc];
      const _Float16 h1 = (_Float16)v1;
      hi1[j] = h1; lo1[j] = (_Float16)(v1 - (float)h1);
    }
    _Float16* d = bP + (size_t)(c0 + lc) * 3072 + r0 + rq;
    *(f16x8*)d = hi0;           *(f16x8*)(d + 8) = hi1;
    *(f16x8*)(d + 1024) = lo0;  *(f16x8*)(d + 1032) = lo1;
    *(f16x8*)(d + 2048) = hi0;  *(f16x8*)(d + 2056) = hi1;
    return;
  }
  // --- tconv: transpose+convert 1024x1024 f32 -> bf16, 18 matrices ---
  const int c = bid - 8256;
  const int m = c >> 8;
  const int t2 = c & 255;
  const int c0 = (t2 & 15) << 6;
  const int r0 = (t2 >> 4) << 6;
  const size_t msz = (size_t)HD * HD;
  const float* src; u16* dst;
  if (m < 8)       { src = ew1 + (size_t)m * msz;       dst = ew1t + (size_t)m * msz; }
  else if (m < 16) { src = ew2 + (size_t)(m - 8) * msz; dst = ew2t + (size_t)(m - 8) * msz; }
  else if (m == 16){ src = uw1;                          dst = uw1t; }
  else             { src = uw2;                          dst = uw2t; }
  {
    const int lr = tid >> 2, q = (tid & 3) << 4;
    const float* s = src + (size_t)(r0 + lr) * HD + c0 + q;
#pragma unroll
    for (int j = 0; j < 16; j += 4) {
      const float4 v = *(const float4*)(s + j);
      tb[lr][q + j] = v.x; tb[lr][q + j + 1] = v.y;
      tb[lr][q + j + 2] = v.z; tb[lr][q + j + 3] = v.w;
    }
  }
  __syncthreads();
  {
    const int lc = tid >> 2, rq = (tid & 3) << 4;
    u16x8 o0, o1;
#pragma unroll
    for (int j = 0; j < 8; ++j) o0[j] = f2bf(tb[rq + j][lc]);
#pragma unroll
    for (int j = 0; j < 8; ++j) o1[j] = f2bf(tb[rq + 8 + j][lc]);
    u16* d = dst + (size_t)(c0 + lc) * HD + r0 + rq;
    *(u16x8*)d = o0;
    *(u16x8*)(d + 8) = o1;
  }
}

// ---------------- Router GEMM: hidden[p][s] = relu(3-term hi/lo fp16 MFMA + sb1), f32 out ----------------
__global__ __launch_bounds__(256) void rgemm_kernel(
    const _Float16* __restrict__ aP, const _Float16* __restrict__ bP,
    const float* __restrict__ sb1, float* __restrict__ hidden) {
  const int p = blockIdx.x;
  const int L = (p & 7) * 64 + (p >> 3);
  const int jt = L & 3;           // 64-col tile
  const int row0 = (L >> 2) << 7; // 128-row tile

  __shared__ _Float16 sA[2][128 * 32];
  __shared__ _Float16 sB[2][64 * 32];

  const int tid = threadIdx.x, lane = tid & 63, wave = tid >> 6;
  const int wr = (wave >> 1) << 6, wc = (wave & 1) << 5;
  const int smrow = tid >> 2, skoff = (((tid & 3) ^ ((tid >> 3) & 3)) << 3);
  const _Float16* ar0 = aP + ((size_t)(row0 + smrow) << 11) + skoff;
  const _Float16* ar1 = aP + ((size_t)(row0 + smrow + 64) << 11) + skoff;
  const _Float16* br  = bP + (size_t)((jt << 6) + smrow) * 3072 + skoff;
  const int ldsoff = wave << 10;

  f32x4 acc[4][2];
#pragma unroll
  for (int i = 0; i < 4; ++i)
#pragma unroll
    for (int j = 0; j < 2; ++j) acc[i][j] = (f32x4){0.f, 0.f, 0.f, 0.f};

  gload16(ar0, (char*)sA[0] + ldsoff);
  gload16(ar1, (char*)sA[0] + 4096 + ldsoff);
  gload16(br,  (char*)sB[0] + ldsoff);

  const int sl = (((lane >> 4) ^ ((lane >> 1) & 3)) << 3);
  const int afrag = (wr + (lane & 15)) * 32 + sl;
  const int bfrag = (wc + (lane & 15)) * 32 + sl;

#pragma unroll
  for (int ks = 0; ks < 96; ++ks) {
    const int buf = ks & 1;
    __syncthreads();
    if (ks + 1 < 96) {
      const int k1 = ks + 1;
      const int pa = (k1 < 64) ? ((k1 & 31) << 5) : (1024 + ((k1 - 64) << 5));
      gload16(ar0 + pa, (char*)sA[buf ^ 1] + ldsoff);
      gload16(ar1 + pa, (char*)sA[buf ^ 1] + 4096 + ldsoff);
      gload16(br + (k1 << 5), (char*)sB[buf ^ 1] + ldsoff);
    }
    f16x8 av[4], bv[2];
#pragma unroll
    for (int f = 0; f < 4; ++f) av[f] = *(const f16x8*)&sA[buf][afrag + f * 512];
#pragma unroll
    for (int f = 0; f < 2; ++f) bv[f] = *(const f16x8*)&sB[buf][bfrag + f * 512];
#pragma unroll
    for (int i = 0; i < 4; ++i)
#pragma unroll
      for (int j = 0; j < 2; ++j)
        acc[i][j] = __builtin_amdgcn_mfma_f32_16x16x32_f16(av[i], bv[j], acc[i][j], 0, 0, 0);
  }

  const int lc = lane & 15, lr4 = (lane >> 4) << 2;
#pragma unroll
  for (int j = 0; j < 2; ++j) {
    const int c = (jt << 6) + wc + (j << 4) + lc;
    const float bias = sb1[c];
#pragma unroll
    for (int i = 0; i < 4; ++i) {
      const int rl = wr + (i << 4) + lr4;
#pragma unroll
      for (int q = 0; q < 4; ++q)
        hidden[((size_t)(row0 + rl + q) << 8) + c] = fmaxf(acc[i][j][q] + bias, 0.f);
    }
  }
}

// ---------------- Logits layer-2 + argmax + histogram + fused scan (last block) ----------------
__global__ __launch_bounds__(256) void logits_kernel(
    const float* __restrict__ hidden, const float* __restrict__ sw2,
    const float* __restrict__ sb2, int* __restrict__ routes, int* meta) {
  __shared__ float logl[32][8];
  const int tid = threadIdx.x;
  const int tok0 = blockIdx.x << 5;
  const int tl = tid >> 3, e2 = tid & 7;
  const float* hp = hidden + ((size_t)(tok0 + tl) << 8);
  float a0 = 0.f, a1 = 0.f, a2 = 0.f, a3 = 0.f;
  for (int q = 0; q < SD; q += 8) {
    const float4 h0 = *(const float4*)&hp[q];
    const float4 h1 = *(const float4*)&hp[q + 4];
    a0 = fmaf(h0.x, sw2[((q + 0) << 3) + e2], a0);
    a1 = fmaf(h0.y, sw2[((q + 1) << 3) + e2], a1);
    a2 = fmaf(h0.z, sw2[((q + 2) << 3) + e2], a2);
    a3 = fmaf(h0.w, sw2[((q + 3) << 3) + e2], a3);
    a0 = fmaf(h1.x, sw2[((q + 4) << 3) + e2], a0);
    a1 = fmaf(h1.y, sw2[((q + 5) << 3) + e2], a1);
    a2 = fmaf(h1.z, sw2[((q + 6) << 3) + e2], a2);
    a3 = fmaf(h1.w, sw2[((q + 7) << 3) + e2], a3);
  }
  logl[tl][e2] = (a0 + a1) + (a2 + a3) + sb2[e2];
  __syncthreads();
  if (tid < 32) {
    float best = logl[tid][0]; int be = 0;
#pragma unroll
    for (int e = 1; e < 8; ++e) {
      const float v = logl[tid][e];
      if (v > best) { best = v; be = e; }
    }
    routes[tok0 + tid] = be;
    atomicAdd(&meta[be], 1);
  }
  // last-block-done: fused scan (replaces scan_kernel launch)
  __syncthreads();
  if (tid == 0) {
    __threadfence();
    const int done = atomicAdd(&meta[26], 1);
    if (done == (int)gridDim.x - 1) {
      int cnt[NE];
#pragma unroll
      for (int e = 0; e < NE; ++e) cnt[e] = atomicAdd(&meta[e], 0);
      int off = 0;
      for (int e = 0; e < NE; ++e) { meta[16 + e] = off; off += cnt[e]; }
      meta[24] = off;
      int nt = 0;
      for (int e = 0; e < NE; ++e) {
        const int s = meta[16 + e], en = meta[16 + e + 1];
        for (int r0 = s; r0 < en; r0 += 128) {
          meta[32 + nt] = e; meta[192 + nt] = r0; meta[352 + nt] = en; ++nt;
        }
      }
      meta[25] = nt;
      __threadfence();
    }
  }
}

// ---------------- Build permutation: two-level counting (r13) ----------------
// 16384 same-line global atomics -> 512 (8 per block). LDS histogram + LDS
// ranks; intra-expert order is arbitrary (grouping is all correctness needs).
__global__ __launch_bounds__(256) void perm_kernel(
    const int* __restrict__ routes, int* meta, int* __restrict__ perm) {
  __shared__ int lcnt[NE], lbase[NE], lcur[NE];
  const int tid = threadIdx.x;
  if (tid < NE) { lcnt[tid] = 0; lcur[tid] = 0; }
  __syncthreads();
  const int b = blockIdx.x * 256 + tid;
  const int r = routes[b];
  atomicAdd(&lcnt[r], 1);
  __syncthreads();
  if (tid < NE)
    lbase[tid] = meta[16 + tid] + atomicAdd(&meta[8 + tid], lcnt[tid]);
  __syncthreads();
  const int rank = atomicAdd(&lcur[r], 1);
  perm[lbase[r] + rank] = b;
}

// ---------------- Gather x rows into grouped order, f32 -> bf16 ----------------
__global__ __launch_bounds__(256) void gatherx_kernel(
    const float* __restrict__ x, const int* __restrict__ perm, u16* __restrict__ xg) {
  const int t = blockIdx.x * 256 + threadIdx.x;
  const int p = t >> 7;
  const int j = (t & 127) << 3;
  const int tok = perm[p];
  const float* s = &x[((size_t)tok << 10) + j];
  const float4 a = *(const float4*)s;
  const float4 b = *(const float4*)(s + 4);
  u16x8 o;
  o[0] = f2bf(a.x); o[1] = f2bf(a.y); o[2] = f2bf(a.z); o[3] = f2bf(a.w);
  o[4] = f2bf(b.x); o[5] = f2bf(b.y); o[6] = f2bf(b.z); o[7] = f2bf(b.w);
  *(u16x8*)&xg[((size_t)p << 10) + j] = o;
}

// ---------------- GEMM1: hid[p][0:2048] = relu(xg[p] @ [ew1[e] | uw1] + eb1[e]/ub1) ----------------
__global__ __launch_bounds__(256) void gemm1_kernel(
    const u16* __restrict__ xg, const u16* __restrict__ ew1t,
    const u16* __restrict__ uw1t, const float* __restrict__ eb1,
    const float* __restrict__ ub1, const int* __restrict__ meta,
    u16* __restrict__ hid) {
  const int nt = meta[25];
  // XCD-chunked, mt-major: grid 2160 = 16 jt x 135 mt
  const int pb = blockIdx.x;
  const int L = (pb & 7) * 270 + (pb >> 3);
  const int mt = L >> 4;
  const int jt = L & 15;
  if (mt >= nt) return;
  const int e = meta[32 + mt], row0 = meta[192 + mt], gend = meta[352 + mt];
  const u16* wbase = (jt < 8)
      ? ew1t + ((size_t)e << 20) + ((size_t)(jt << 7) << 10)
      : uw1t + ((size_t)((jt - 8) << 7) << 10);

  // 32KB unified LDS: K-loop sA/sB; epilogue reuses as [128][128] u16 tile.
  __shared__ u16 smem[16384];
  u16 (*sA)[4096] = (u16(*)[4096])smem;
  u16 (*sB)[4096] = (u16(*)[4096])(smem + 8192);

  const int tid = threadIdx.x;
  const int lane = tid & 63;
  const int wave = tid >> 6;
  const int wr = (wave >> 1) << 6;
  const int wc = (wave & 1) << 6;

  const int smrow = tid >> 2;
  const int skoff = (((tid & 3) ^ ((tid >> 3) & 3)) << 3);
  const u16* ap0 = xg + (((size_t)(row0 + smrow)) << 10) + skoff;
  const u16* ap1 = xg + (((size_t)(row0 + smrow + 64)) << 10) + skoff;
  const u16* bp0 = wbase + (((size_t)smrow) << 10) + skoff;
  const u16* bp1 = wbase + (((size_t)(smrow + 64)) << 10) + skoff;
  const int ldsoff = wave << 10;

  f32x4 acc[4][4];
#pragma unroll
  for (int i = 0; i < 4; ++i)
#pragma unroll
    for (int j = 0; j < 4; ++j) acc[i][j] = (f32x4){0.f, 0.f, 0.f, 0.f};

  gload16(ap0, (char*)sA[0] + ldsoff);
  gload16(ap1, (char*)sA[0] + 4096 + ldsoff);
  gload16(bp0, (char*)sB[0] + ldsoff);
  gload16(bp1, (char*)sB[0] + 4096 + ldsoff);

  const int sl = (((lane >> 4) ^ ((lane >> 1) & 3)) << 3);
  const int afrag = (wr + (lane & 15)) * 32 + sl;
  const int bfrag = (wc + (lane & 15)) * 32 + sl;

#pragma unroll
  for (int ks = 0; ks < 32; ++ks) {
    const int buf = ks & 1;
    __syncthreads();
    if (ks + 1 < 32) {
      const int k1 = (ks + 1) << 5;
      gload16(ap0 + k1, (char*)sA[buf ^ 1] + ldsoff);
      gload16(ap1 + k1, (char*)sA[buf ^ 1] + 4096 + ldsoff);
      gload16(bp0 + k1, (char*)sB[buf ^ 1] + ldsoff);
      gload16(bp1 + k1, (char*)sB[buf ^ 1] + 4096 + ldsoff);
    }
    bf16x8 av[4], bv[4];
#pragma unroll
    for (int f = 0; f < 4; ++f) {
      av[f] = *(const bf16x8*)&sA[buf][afrag + f * 512];
      bv[f] = *(const bf16x8*)&sB[buf][bfrag + f * 512];
    }
#pragma unroll
    for (int i = 0; i < 4; ++i)
#pragma unroll
      for (int j = 0; j < 4; ++j)
        acc[i][j] = __builtin_amdgcn_mfma_f32_16x16x32_bf16(av[i], bv[j], acc[i][j], 0, 0, 0);
  }

  // --- epilogue: bias+relu+cvt -> LDS tile, then 256B-contiguous stores ---
  __syncthreads();
  {
    const int lc = lane & 15;
    const int lr4 = (lane >> 4) << 2;
#pragma unroll
    for (int j = 0; j < 4; ++j) {
      const int c = wc + (j << 4) + lc;           // local col 0..127
      const int gc = (jt << 7) + c;
      const float bias = (gc < 1024) ? eb1[(e << 10) + gc] : ub1[gc - 1024];
#pragma unroll
      for (int i = 0; i < 4; ++i) {
        const int rl = wr + (i << 4) + lr4;
#pragma unroll
        for (int q = 0; q < 4; ++q)
          smem[(rl + q) * 128 + c] = f2bf(fmaxf(acc[i][j][q] + bias, 0.f));
      }
    }
  }
  __syncthreads();
  {
    const int l16 = lane & 15, rg = lane >> 4;
#pragma unroll
    for (int it = 0; it < 8; ++it) {
      const int lr = (wave << 5) + (it << 2) + rg;   // local row 0..127
      const int p = row0 + lr;
      const u16x8 v = *(const u16x8*)&smem[lr * 128 + (l16 << 3)];
      if (p < gend)
        *(u16x8*)&hid[((size_t)p << 11) + (jt << 7) + (l16 << 3)] = v;
    }
  }
}

// ---------------- GEMM2: out[perm[p]][c] = hid[p] @ [ew2[e]; uw2] + eb2[e] + ub2 ----------------
__global__ __launch_bounds__(256) void gemm2_kernel(
    const u16* __restrict__ hid, const u16* __restrict__ ew2t,
    const u16* __restrict__ uw2t, const float* __restrict__ eb2,
    const float* __restrict__ ub2, const int* __restrict__ meta,
    const int* __restrict__ perm, float* __restrict__ out) {
  const int nt = meta[25];
  // XCD-chunked, mt-major: grid 1080 = 8 jt x 135 mt
  const int pb = blockIdx.x;
  const int L = (pb & 7) * 135 + (pb >> 3);
  const int mt = L >> 3;
  const int jt = L & 7;
  if (mt >= nt) return;
  const int e = meta[32 + mt], row0 = meta[192 + mt], gend = meta[352 + mt];
  const int n0 = jt << 7;

  // 32KB unified LDS: K-loop sA/sB; epilogue reuses as [64][128] f32 half-tile.
  __shared__ u16 smem[16384];
  u16 (*sA)[4096] = (u16(*)[4096])smem;
  u16 (*sB)[4096] = (u16(*)[4096])(smem + 8192);
  float* smemf = (float*)smem;

  const int tid = threadIdx.x;
  const int lane = tid & 63;
  const int wave = tid >> 6;
  const int wr = (wave >> 1) << 6;
  const int wc = (wave & 1) << 6;

  const int smrow = tid >> 2;
  const int skoff = (((tid & 3) ^ ((tid >> 3) & 3)) << 3);
  const u16* ap0 = hid + (((size_t)(row0 + smrow)) << 11) + skoff;
  const u16* ap1 = hid + (((size_t)(row0 + smrow + 64)) << 11) + skoff;
  const u16* ebase = ew2t + ((size_t)e << 20);
  const size_t brow0 = (((size_t)(n0 + smrow)) << 10) + skoff;
  const size_t brow1 = (((size_t)(n0 + smrow + 64)) << 10) + skoff;
  const int ldsoff = wave << 10;

  f32x4 acc[4][4];
#pragma unroll
  for (int i = 0; i < 4; ++i)
#pragma unroll
    for (int j = 0; j < 4; ++j) acc[i][j] = (f32x4){0.f, 0.f, 0.f, 0.f};

  gload16(ap0, (char*)sA[0] + ldsoff);
  gload16(ap1, (char*)sA[0] + 4096 + ldsoff);
  gload16(ebase + brow0, (char*)sB[0] + ldsoff);
  gload16(ebase + brow1, (char*)sB[0] + 4096 + ldsoff);

  const int sl = (((lane >> 4) ^ ((lane >> 1) & 3)) << 3);
  const int afrag = (wr + (lane & 15)) * 32 + sl;
  const int bfrag = (wc + (lane & 15)) * 32 + sl;

#pragma unroll
  for (int ks = 0; ks < 64; ++ks) {
    const int buf = ks & 1;
    __syncthreads();
    if (ks + 1 < 64) {
      const int k1 = (ks + 1) << 5;
      const u16* bb = (k1 < 1024) ? ebase : uw2t;
      const int kk = k1 & 1023;
      gload16(ap0 + k1, (char*)sA[buf ^ 1] + ldsoff);
      gload16(ap1 + k1, (char*)sA[buf ^ 1] + 4096 + ldsoff);
      gload16(bb + brow0 + kk, (char*)sB[buf ^ 1] + ldsoff);
      gload16(bb + brow1 + kk, (char*)sB[buf ^ 1] + 4096 + ldsoff);
    }
    bf16x8 av[4], bv[4];
#pragma unroll
    for (int f = 0; f < 4; ++f) {
      av[f] = *(const bf16x8*)&sA[buf][afrag + f * 512];
      bv[f] = *(const bf16x8*)&sB[buf][bfrag + f * 512];
    }
#pragma unroll
    for (int i = 0; i < 4; ++i)
#pragma unroll
      for (int j = 0; j < 4; ++j)
        acc[i][j] = __builtin_amdgcn_mfma_f32_16x16x32_bf16(av[i], bv[j], acc[i][j], 0, 0, 0);
  }

  // --- epilogue: 2 half-passes via [64][128] f32 LDS tile, 512B/row stores ---
  const int lc = lane & 15;
  const int lr4 = (lane >> 4) << 2;
  float b2v[4];
#pragma unroll
  for (int j = 0; j < 4; ++j) {
    const int c = n0 + wc + (j << 4) + lc;
    b2v[j] = eb2[(e << 10) + c] + ub2[c];
  }
  __syncthreads();
#pragma unroll
  for (int pass = 0; pass < 2; ++pass) {
    if ((wave >> 1) == pass) {
#pragma unroll
      for (int j = 0; j < 4; ++j) {
        const int c = wc + (j << 4) + lc;         // local col 0..127
#pragma unroll
        for (int i = 0; i < 4; ++i) {
          const int lrl = (i << 4) + lr4;          // local row 0..63
#pragma unroll
          for (int q = 0; q < 4; ++q)
            smemf[(lrl + q) * 128 + c] = acc[i][j][q] + b2v[j];
        }
      }
    }
    __syncthreads();
#pragma unroll
    for (int it = 0; it < 8; ++it) {
      const int lrl = (it << 3) + (wave << 1) + (lane >> 5);  // 0..63
      const int p = row0 + (pass << 6) + lrl;
      const float4 v = *(const float4*)&smemf[lrl * 128 + ((lane & 31) << 2)];
      if (p < gend)
        *(float4*)&out[((size_t)perm[p] << 10) + n0 + ((lane & 31) << 2)] = v;
    }
    __syncthreads();
  }
}

extern "C" void kernel_launch(void* const* d_in, const int* in_sizes, int n_in,
                              void* d_out, int out_size, void* d_ws, size_t ws_size,
                              hipStream_t stream) {
  const float* x   = (const float*)d_in[0];
  const float* ue  = (const float*)d_in[1];
  const float* sw1 = (const float*)d_in[2];
  const float* sb1 = (const float*)d_in[3];
  const float* sw2 = (const float*)d_in[4];
  const float* sb2 = (const float*)d_in[5];
  const float* ew1 = (const float*)d_in[6];
  const float* eb1 = (const float*)d_in[7];
  const float* ew2 = (const float*)d_in[8];
  const float* eb2 = (const float*)d_in[9];
  const float* uw1 = (const float*)d_in[10];
  const float* ub1 = (const float*)d_in[11];
  const float* uw2 = (const float*)d_in[12];
  const float* ub2 = (const float*)d_in[13];
  float* out = (float*)d_out;

  char* w = (char*)d_ws;
  int* meta = (int*)w;    w += 4096;
  int* routes = (int*)w;  w += NTOK * 4;
  int* perm = (int*)w;    w += NTOK * 4;
  char* region = w;
  u16* xg   = (u16*)region;                                             // 33,816,576 B
  u16* ew1t = (u16*)(region + 33816576ull);                             // 16 MiB
  u16* ew2t = (u16*)(region + 33816576ull + 16777216ull);               // 16 MiB
  u16* uw1t = (u16*)(region + 33816576ull + 2 * 16777216ull);           // 2 MiB
  u16* uw2t = (u16*)(region + 33816576ull + 2 * 16777216ull + 2097152ull);
  u16* hid  = (u16*)(region + 33816576ull + 2 * 16777216ull + 2 * 2097152ull);  // 67,633,152 B
  const size_t region_sz = 33816576ull + 2 * 16777216ull + 2 * 2097152ull + 67633152ull;
  // router-phase aliases live in the (dead-until-gemm1) hid region / xg region:
  _Float16* aP     = (_Float16*)(region + 33816576ull + 2 * 16777216ull + 2 * 2097152ull);
  float* hidden32  = (float*)region;
  _Float16* bP     = (_Float16*)(region + 16777216ull);
  if (135168ull + region_sz > ws_size) return;

  hipMemsetAsync(meta, 0, 4096, stream);
  prep_kernel<<<12864, 256, 0, stream>>>(ue, aP, sw1, bP, ew1, ew2, uw1, uw2,
                                         ew1t, ew2t, uw1t, uw2t);
  rgemm_kernel<<<512, 256, 0, stream>>>(aP, bP, sb1, hidden32);
  logits_kernel<<<NTOK / 32, 256, 0, stream>>>(hidden32, sw2, sb2, routes, meta);
  perm_kernel<<<NTOK / 256, 256, 0, stream>>>(routes, meta, perm);
  gatherx_kernel<<<(NTOK * 128) / 256, 256, 0, stream>>>(x, perm, xg);
  gemm1_kernel<<<2160, 256, 0, stream>>>(xg, ew1t, uw1t, eb1, ub1, meta, hid);
  gemm2_kernel<<<1080, 256, 0, stream>>>(hid, ew2t, uw2t, eb2, ub2, meta, perm, out);
}

// Round 15
// 353.277 us; speedup vs baseline: 1.7436x; 1.2503x over previous
//
#include <hip/hip_runtime.h>
#include <stdint.h>

#define NTOK 16384
#define HD   1024
#define SD   256
#define NE   8

typedef short bf16x8 __attribute__((ext_vector_type(8)));
typedef _Float16 f16x8 __attribute__((ext_vector_type(8)));
typedef float f32x4 __attribute__((ext_vector_type(4)));
typedef unsigned short u16;
typedef unsigned short u16x8 __attribute__((ext_vector_type(8)));

__device__ __forceinline__ u16 f2bf(float f) {
  union { float f; unsigned u; } v; v.f = f;
  return (u16)((v.u + 0x7fffu + ((v.u >> 16) & 1u)) >> 16);
}

__device__ __forceinline__ void gload16(const void* g, void* l) {
  __builtin_amdgcn_global_load_lds((const __attribute__((address_space(1))) void*)g,
                                   (__attribute__((address_space(3))) void*)l,
                                   16, 0, 0);
}

// meta layout (ints): [0..7] counts, [8..15] cursors, [16..24] offsets,
// [25] ntiles, [26] logits-done counter, [32..191] tile_e, [192..351] tile_row0,
// [352..511] tile_end

// LDS chunk-XOR swizzle (all GEMMs): conflict-free ds_read_b128 with unchanged
// VMEM coalescing (verified: conflicts 8.7M -> 0). K-loops fully unrolled (r8).
// r11/r12: LDS-staged epilogues -> full-line stores (gemm1+gemm2, -50us total).
// r13/r14 FINDING: ANY per-token atomic on the 8-counter meta line is a ~125us
// serial chain (16384 x ~8ns cross-XCD line bounce). perm fixed r13 (-117us);
// logits had the SAME pattern (121us) -> fixed r15 identically: 128 tok/block,
// LDS histogram, 8 global atomics/block (1024 total).
// r12 LESSON: don't fuse work into hot GEMMs if it grows VGPR/LDS (occupancy).
// r10 LESSON: rgemm grid 512 (2 blocks/CU). r9 LESSON: no atomic+barrier chains.

// ---------------- Fused prep: aprep (8192 blk) + bprep (64 blk) + tconv (4608 blk) ----------------
__global__ __launch_bounds__(256) void prep_kernel(
    const float* __restrict__ ue, _Float16* __restrict__ aP,
    const float* __restrict__ sw1, _Float16* __restrict__ bP,
    const float* __restrict__ ew1, const float* __restrict__ ew2,
    const float* __restrict__ uw1, const float* __restrict__ uw2,
    u16* __restrict__ ew1t, u16* __restrict__ ew2t,
    u16* __restrict__ uw1t, u16* __restrict__ uw2t) {
  const int bid = blockIdx.x;
  const int tid = threadIdx.x;
  if (bid < 8192) {
    // --- aprep: ue f32 -> A' = [hi | lo] fp16, row stride 2048 ---
    const int t = bid * 256 + tid;
    const int p = t >> 7;
    const int h = (t & 127) << 3;
    const float* s = ue + ((size_t)p << 10) + h;
    const float4 a = *(const float4*)s;
    const float4 b = *(const float4*)(s + 4);
    float v[8] = {a.x, a.y, a.z, a.w, b.x, b.y, b.z, b.w};
    f16x8 hi, lo;
#pragma unroll
    for (int j = 0; j < 8; ++j) {
      const _Float16 h16 = (_Float16)v[j];
      hi[j] = h16;
      lo[j] = (_Float16)(v[j] - (float)h16);
    }
    _Float16* d = aP + ((size_t)p << 11) + h;
    *(f16x8*)d = hi;
    *(f16x8*)(d + 1024) = lo;
    return;
  }
  __shared__ float tb[64][65];
  if (bid < 8256) {
    // --- bprep: sw1 [1024][256] f32 -> B' [256][3072] fp16 = [hi|lo|hi] ---
    const int b = bid - 8192;
    const int c0 = (b & 3) << 6;
    const int r0 = (b >> 2) << 6;
    {
      const int lr = tid >> 2, q = (tid & 3) << 4;
      const float* s = sw1 + (size_t)(r0 + lr) * SD + c0 + q;
#pragma unroll
      for (int j = 0; j < 16; j += 4) {
        const float4 v = *(const float4*)(s + j);
        tb[lr][q + j] = v.x; tb[lr][q + j + 1] = v.y;
        tb[lr][q + j + 2] = v.z; tb[lr][q + j + 3] = v.w;
      }
    }
    __syncthreads();
    const int lc = tid >> 2, rq = (tid & 3) << 4;
    f16x8 hi0, hi1, lo0, lo1;
#pragma unroll
    for (int j = 0; j < 8; ++j) {
      const float v0 = tb[rq + j][lc];
      const _Float16 h0 = (_Float16)v0;
      hi0[j] = h0; lo0[j] = (_Float16)(v0 - (float)h0);
      const float v1 = tb[rq + 8 + j][lc];
      const _Float16 h1 = (_Float16)v1;
      hi1[j] = h1; lo1[j] = (_Float16)(v1 - (float)h1);
    }
    _Float16* d = bP + (size_t)(c0 + lc) * 3072 + r0 + rq;
    *(f16x8*)d = hi0;           *(f16x8*)(d + 8) = hi1;
    *(f16x8*)(d + 1024) = lo0;  *(f16x8*)(d + 1032) = lo1;
    *(f16x8*)(d + 2048) = hi0;  *(f16x8*)(d + 2056) = hi1;
    return;
  }
  // --- tconv: transpose+convert 1024x1024 f32 -> bf16, 18 matrices ---
  const int c = bid - 8256;
  const int m = c >> 8;
  const int t2 = c & 255;
  const int c0 = (t2 & 15) << 6;
  const int r0 = (t2 >> 4) << 6;
  const size_t msz = (size_t)HD * HD;
  const float* src; u16* dst;
  if (m < 8)       { src = ew1 + (size_t)m * msz;       dst = ew1t + (size_t)m * msz; }
  else if (m < 16) { src = ew2 + (size_t)(m - 8) * msz; dst = ew2t + (size_t)(m - 8) * msz; }
  else if (m == 16){ src = uw1;                          dst = uw1t; }
  else             { src = uw2;                          dst = uw2t; }
  {
    const int lr = tid >> 2, q = (tid & 3) << 4;
    const float* s = src + (size_t)(r0 + lr) * HD + c0 + q;
#pragma unroll
    for (int j = 0; j < 16; j += 4) {
      const float4 v = *(const float4*)(s + j);
      tb[lr][q + j] = v.x; tb[lr][q + j + 1] = v.y;
      tb[lr][q + j + 2] = v.z; tb[lr][q + j + 3] = v.w;
    }
  }
  __syncthreads();
  {
    const int lc = tid >> 2, rq = (tid & 3) << 4;
    u16x8 o0, o1;
#pragma unroll
    for (int j = 0; j < 8; ++j) o0[j] = f2bf(tb[rq + j][lc]);
#pragma unroll
    for (int j = 0; j < 8; ++j) o1[j] = f2bf(tb[rq + 8 + j][lc]);
    u16* d = dst + (size_t)(c0 + lc) * HD + r0 + rq;
    *(u16x8*)d = o0;
    *(u16x8*)(d + 8) = o1;
  }
}

// ---------------- Router GEMM: hidden[p][s] = relu(3-term hi/lo fp16 MFMA + sb1), f32 out ----------------
__global__ __launch_bounds__(256) void rgemm_kernel(
    const _Float16* __restrict__ aP, const _Float16* __restrict__ bP,
    const float* __restrict__ sb1, float* __restrict__ hidden) {
  const int p = blockIdx.x;
  const int L = (p & 7) * 64 + (p >> 3);
  const int jt = L & 3;           // 64-col tile
  const int row0 = (L >> 2) << 7; // 128-row tile

  __shared__ _Float16 sA[2][128 * 32];
  __shared__ _Float16 sB[2][64 * 32];

  const int tid = threadIdx.x, lane = tid & 63, wave = tid >> 6;
  const int wr = (wave >> 1) << 6, wc = (wave & 1) << 5;
  const int smrow = tid >> 2, skoff = (((tid & 3) ^ ((tid >> 3) & 3)) << 3);
  const _Float16* ar0 = aP + ((size_t)(row0 + smrow) << 11) + skoff;
  const _Float16* ar1 = aP + ((size_t)(row0 + smrow + 64) << 11) + skoff;
  const _Float16* br  = bP + (size_t)((jt << 6) + smrow) * 3072 + skoff;
  const int ldsoff = wave << 10;

  f32x4 acc[4][2];
#pragma unroll
  for (int i = 0; i < 4; ++i)
#pragma unroll
    for (int j = 0; j < 2; ++j) acc[i][j] = (f32x4){0.f, 0.f, 0.f, 0.f};

  gload16(ar0, (char*)sA[0] + ldsoff);
  gload16(ar1, (char*)sA[0] + 4096 + ldsoff);
  gload16(br,  (char*)sB[0] + ldsoff);

  const int sl = (((lane >> 4) ^ ((lane >> 1) & 3)) << 3);
  const int afrag = (wr + (lane & 15)) * 32 + sl;
  const int bfrag = (wc + (lane & 15)) * 32 + sl;

#pragma unroll
  for (int ks = 0; ks < 96; ++ks) {
    const int buf = ks & 1;
    __syncthreads();
    if (ks + 1 < 96) {
      const int k1 = ks + 1;
      const int pa = (k1 < 64) ? ((k1 & 31) << 5) : (1024 + ((k1 - 64) << 5));
      gload16(ar0 + pa, (char*)sA[buf ^ 1] + ldsoff);
      gload16(ar1 + pa, (char*)sA[buf ^ 1] + 4096 + ldsoff);
      gload16(br + (k1 << 5), (char*)sB[buf ^ 1] + ldsoff);
    }
    f16x8 av[4], bv[2];
#pragma unroll
    for (int f = 0; f < 4; ++f) av[f] = *(const f16x8*)&sA[buf][afrag + f * 512];
#pragma unroll
    for (int f = 0; f < 2; ++f) bv[f] = *(const f16x8*)&sB[buf][bfrag + f * 512];
#pragma unroll
    for (int i = 0; i < 4; ++i)
#pragma unroll
      for (int j = 0; j < 2; ++j)
        acc[i][j] = __builtin_amdgcn_mfma_f32_16x16x32_f16(av[i], bv[j], acc[i][j], 0, 0, 0);
  }

  const int lc = lane & 15, lr4 = (lane >> 4) << 2;
#pragma unroll
  for (int j = 0; j < 2; ++j) {
    const int c = (jt << 6) + wc + (j << 4) + lc;
    const float bias = sb1[c];
#pragma unroll
    for (int i = 0; i < 4; ++i) {
      const int rl = wr + (i << 4) + lr4;
#pragma unroll
      for (int q = 0; q < 4; ++q)
        hidden[((size_t)(row0 + rl + q) << 8) + c] = fmaxf(acc[i][j][q] + bias, 0.f);
    }
  }
}

// ---------------- Logits: 128 tok/block, LDS histogram (r15), fused scan ----------------
__global__ __launch_bounds__(256) void logits_kernel(
    const float* __restrict__ hidden, const float* __restrict__ sw2,
    const float* __restrict__ sb2, int* __restrict__ routes, int* meta) {
  __shared__ float logl[32][8];
  __shared__ int lhist[NE];
  const int tid = threadIdx.x;
  if (tid < NE) lhist[tid] = 0;
  const int tok0 = blockIdx.x << 7;     // 128 tokens per block
  const int tl = tid >> 3, e2 = tid & 7;
  __syncthreads();
#pragma unroll 1
  for (int g4 = 0; g4 < 4; ++g4) {
    const float* hp = hidden + ((size_t)(tok0 + (g4 << 5) + tl) << 8);
    float a0 = 0.f, a1 = 0.f, a2 = 0.f, a3 = 0.f;
    for (int q = 0; q < SD; q += 8) {
      const float4 h0 = *(const float4*)&hp[q];
      const float4 h1 = *(const float4*)&hp[q + 4];
      a0 = fmaf(h0.x, sw2[((q + 0) << 3) + e2], a0);
      a1 = fmaf(h0.y, sw2[((q + 1) << 3) + e2], a1);
      a2 = fmaf(h0.z, sw2[((q + 2) << 3) + e2], a2);
      a3 = fmaf(h0.w, sw2[((q + 3) << 3) + e2], a3);
      a0 = fmaf(h1.x, sw2[((q + 4) << 3) + e2], a0);
      a1 = fmaf(h1.y, sw2[((q + 5) << 3) + e2], a1);
      a2 = fmaf(h1.z, sw2[((q + 6) << 3) + e2], a2);
      a3 = fmaf(h1.w, sw2[((q + 7) << 3) + e2], a3);
    }
    logl[tl][e2] = (a0 + a1) + (a2 + a3) + sb2[e2];
    __syncthreads();
    if (tid < 32) {
      float best = logl[tid][0]; int be = 0;
#pragma unroll
      for (int e = 1; e < 8; ++e) {
        const float v = logl[tid][e];
        if (v > best) { best = v; be = e; }
      }
      routes[tok0 + (g4 << 5) + tid] = be;
      atomicAdd(&lhist[be], 1);
    }
    __syncthreads();
  }
  // 8 global atomics per block (1024 total vs 16384 per-token)
  if (tid < NE) atomicAdd(&meta[tid], lhist[tid]);
  // last-block-done: fused scan
  __syncthreads();
  if (tid == 0) {
    __threadfence();
    const int done = atomicAdd(&meta[26], 1);
    if (done == (int)gridDim.x - 1) {
      int cnt[NE];
#pragma unroll
      for (int e = 0; e < NE; ++e) cnt[e] = atomicAdd(&meta[e], 0);
      int off = 0;
      for (int e = 0; e < NE; ++e) { meta[16 + e] = off; off += cnt[e]; }
      meta[24] = off;
      int nt = 0;
      for (int e = 0; e < NE; ++e) {
        const int s = meta[16 + e], en = meta[16 + e + 1];
        for (int r0 = s; r0 < en; r0 += 128) {
          meta[32 + nt] = e; meta[192 + nt] = r0; meta[352 + nt] = en; ++nt;
        }
      }
      meta[25] = nt;
      __threadfence();
    }
  }
}

// ---------------- Build permutation: two-level counting (r13) ----------------
__global__ __launch_bounds__(256) void perm_kernel(
    const int* __restrict__ routes, int* meta, int* __restrict__ perm) {
  __shared__ int lcnt[NE], lbase[NE], lcur[NE];
  const int tid = threadIdx.x;
  if (tid < NE) { lcnt[tid] = 0; lcur[tid] = 0; }
  __syncthreads();
  const int b = blockIdx.x * 256 + tid;
  const int r = routes[b];
  atomicAdd(&lcnt[r], 1);
  __syncthreads();
  if (tid < NE)
    lbase[tid] = meta[16 + tid] + atomicAdd(&meta[8 + tid], lcnt[tid]);
  __syncthreads();
  const int rank = atomicAdd(&lcur[r], 1);
  perm[lbase[r] + rank] = b;
}

// ---------------- Gather x rows into grouped order, f32 -> bf16 ----------------
__global__ __launch_bounds__(256) void gatherx_kernel(
    const float* __restrict__ x, const int* __restrict__ perm, u16* __restrict__ xg) {
  const int t = blockIdx.x * 256 + threadIdx.x;
  const int p = t >> 7;
  const int j = (t & 127) << 3;
  const int tok = perm[p];
  const float* s = &x[((size_t)tok << 10) + j];
  const float4 a = *(const float4*)s;
  const float4 b = *(const float4*)(s + 4);
  u16x8 o;
  o[0] = f2bf(a.x); o[1] = f2bf(a.y); o[2] = f2bf(a.z); o[3] = f2bf(a.w);
  o[4] = f2bf(b.x); o[5] = f2bf(b.y); o[6] = f2bf(b.z); o[7] = f2bf(b.w);
  *(u16x8*)&xg[((size_t)p << 10) + j] = o;
}

// ---------------- GEMM1: hid[p][0:2048] = relu(xg[p] @ [ew1[e] | uw1] + eb1[e]/ub1) ----------------
__global__ __launch_bounds__(256) void gemm1_kernel(
    const u16* __restrict__ xg, const u16* __restrict__ ew1t,
    const u16* __restrict__ uw1t, const float* __restrict__ eb1,
    const float* __restrict__ ub1, const int* __restrict__ meta,
    u16* __restrict__ hid) {
  const int nt = meta[25];
  // XCD-chunked, mt-major: grid 2160 = 16 jt x 135 mt
  const int pb = blockIdx.x;
  const int L = (pb & 7) * 270 + (pb >> 3);
  const int mt = L >> 4;
  const int jt = L & 15;
  if (mt >= nt) return;
  const int e = meta[32 + mt], row0 = meta[192 + mt], gend = meta[352 + mt];
  const u16* wbase = (jt < 8)
      ? ew1t + ((size_t)e << 20) + ((size_t)(jt << 7) << 10)
      : uw1t + ((size_t)((jt - 8) << 7) << 10);

  // 32KB unified LDS: K-loop sA/sB; epilogue reuses as [128][128] u16 tile.
  __shared__ u16 smem[16384];
  u16 (*sA)[4096] = (u16(*)[4096])smem;
  u16 (*sB)[4096] = (u16(*)[4096])(smem + 8192);

  const int tid = threadIdx.x;
  const int lane = tid & 63;
  const int wave = tid >> 6;
  const int wr = (wave >> 1) << 6;
  const int wc = (wave & 1) << 6;

  const int smrow = tid >> 2;
  const int skoff = (((tid & 3) ^ ((tid >> 3) & 3)) << 3);
  const u16* ap0 = xg + (((size_t)(row0 + smrow)) << 10) + skoff;
  const u16* ap1 = xg + (((size_t)(row0 + smrow + 64)) << 10) + skoff;
  const u16* bp0 = wbase + (((size_t)smrow) << 10) + skoff;
  const u16* bp1 = wbase + (((size_t)(smrow + 64)) << 10) + skoff;
  const int ldsoff = wave << 10;

  f32x4 acc[4][4];
#pragma unroll
  for (int i = 0; i < 4; ++i)
#pragma unroll
    for (int j = 0; j < 4; ++j) acc[i][j] = (f32x4){0.f, 0.f, 0.f, 0.f};

  gload16(ap0, (char*)sA[0] + ldsoff);
  gload16(ap1, (char*)sA[0] + 4096 + ldsoff);
  gload16(bp0, (char*)sB[0] + ldsoff);
  gload16(bp1, (char*)sB[0] + 4096 + ldsoff);

  const int sl = (((lane >> 4) ^ ((lane >> 1) & 3)) << 3);
  const int afrag = (wr + (lane & 15)) * 32 + sl;
  const int bfrag = (wc + (lane & 15)) * 32 + sl;

#pragma unroll
  for (int ks = 0; ks < 32; ++ks) {
    const int buf = ks & 1;
    __syncthreads();
    if (ks + 1 < 32) {
      const int k1 = (ks + 1) << 5;
      gload16(ap0 + k1, (char*)sA[buf ^ 1] + ldsoff);
      gload16(ap1 + k1, (char*)sA[buf ^ 1] + 4096 + ldsoff);
      gload16(bp0 + k1, (char*)sB[buf ^ 1] + ldsoff);
      gload16(bp1 + k1, (char*)sB[buf ^ 1] + 4096 + ldsoff);
    }
    bf16x8 av[4], bv[4];
#pragma unroll
    for (int f = 0; f < 4; ++f) {
      av[f] = *(const bf16x8*)&sA[buf][afrag + f * 512];
      bv[f] = *(const bf16x8*)&sB[buf][bfrag + f * 512];
    }
#pragma unroll
    for (int i = 0; i < 4; ++i)
#pragma unroll
      for (int j = 0; j < 4; ++j)
        acc[i][j] = __builtin_amdgcn_mfma_f32_16x16x32_bf16(av[i], bv[j], acc[i][j], 0, 0, 0);
  }

  // --- epilogue: bias+relu+cvt -> LDS tile, then 256B-contiguous stores ---
  __syncthreads();
  {
    const int lc = lane & 15;
    const int lr4 = (lane >> 4) << 2;
#pragma unroll
    for (int j = 0; j < 4; ++j) {
      const int c = wc + (j << 4) + lc;           // local col 0..127
      const int gc = (jt << 7) + c;
      const float bias = (gc < 1024) ? eb1[(e << 10) + gc] : ub1[gc - 1024];
#pragma unroll
      for (int i = 0; i < 4; ++i) {
        const int rl = wr + (i << 4) + lr4;
#pragma unroll
        for (int q = 0; q < 4; ++q)
          smem[(rl + q) * 128 + c] = f2bf(fmaxf(acc[i][j][q] + bias, 0.f));
      }
    }
  }
  __syncthreads();
  {
    const int l16 = lane & 15, rg = lane >> 4;
#pragma unroll
    for (int it = 0; it < 8; ++it) {
      const int lr = (wave << 5) + (it << 2) + rg;   // local row 0..127
      const int p = row0 + lr;
      const u16x8 v = *(const u16x8*)&smem[lr * 128 + (l16 << 3)];
      if (p < gend)
        *(u16x8*)&hid[((size_t)p << 11) + (jt << 7) + (l16 << 3)] = v;
    }
  }
}

// ---------------- GEMM2: out[perm[p]][c] = hid[p] @ [ew2[e]; uw2] + eb2[e] + ub2 ----------------
__global__ __launch_bounds__(256) void gemm2_kernel(
    const u16* __restrict__ hid, const u16* __restrict__ ew2t,
    const u16* __restrict__ uw2t, const float* __restrict__ eb2,
    const float* __restrict__ ub2, const int* __restrict__ meta,
    const int* __restrict__ perm, float* __restrict__ out) {
  const int nt = meta[25];
  // XCD-chunked, mt-major: grid 1080 = 8 jt x 135 mt
  const int pb = blockIdx.x;
  const int L = (pb & 7) * 135 + (pb >> 3);
  const int mt = L >> 3;
  const int jt = L & 7;
  if (mt >= nt) return;
  const int e = meta[32 + mt], row0 = meta[192 + mt], gend = meta[352 + mt];
  const int n0 = jt << 7;

  // 32KB unified LDS: K-loop sA/sB; epilogue reuses as [64][128] f32 half-tile.
  __shared__ u16 smem[16384];
  u16 (*sA)[4096] = (u16(*)[4096])smem;
  u16 (*sB)[4096] = (u16(*)[4096])(smem + 8192);
  float* smemf = (float*)smem;

  const int tid = threadIdx.x;
  const int lane = tid & 63;
  const int wave = tid >> 6;
  const int wr = (wave >> 1) << 6;
  const int wc = (wave & 1) << 6;

  const int smrow = tid >> 2;
  const int skoff = (((tid & 3) ^ ((tid >> 3) & 3)) << 3);
  const u16* ap0 = hid + (((size_t)(row0 + smrow)) << 11) + skoff;
  const u16* ap1 = hid + (((size_t)(row0 + smrow + 64)) << 11) + skoff;
  const u16* ebase = ew2t + ((size_t)e << 20);
  const size_t brow0 = (((size_t)(n0 + smrow)) << 10) + skoff;
  const size_t brow1 = (((size_t)(n0 + smrow + 64)) << 10) + skoff;
  const int ldsoff = wave << 10;

  f32x4 acc[4][4];
#pragma unroll
  for (int i = 0; i < 4; ++i)
#pragma unroll
    for (int j = 0; j < 4; ++j) acc[i][j] = (f32x4){0.f, 0.f, 0.f, 0.f};

  gload16(ap0, (char*)sA[0] + ldsoff);
  gload16(ap1, (char*)sA[0] + 4096 + ldsoff);
  gload16(ebase + brow0, (char*)sB[0] + ldsoff);
  gload16(ebase + brow1, (char*)sB[0] + 4096 + ldsoff);

  const int sl = (((lane >> 4) ^ ((lane >> 1) & 3)) << 3);
  const int afrag = (wr + (lane & 15)) * 32 + sl;
  const int bfrag = (wc + (lane & 15)) * 32 + sl;

#pragma unroll
  for (int ks = 0; ks < 64; ++ks) {
    const int buf = ks & 1;
    __syncthreads();
    if (ks + 1 < 64) {
      const int k1 = (ks + 1) << 5;
      const u16* bb = (k1 < 1024) ? ebase : uw2t;
      const int kk = k1 & 1023;
      gload16(ap0 + k1, (char*)sA[buf ^ 1] + ldsoff);
      gload16(ap1 + k1, (char*)sA[buf ^ 1] + 4096 + ldsoff);
      gload16(bb + brow0 + kk, (char*)sB[buf ^ 1] + ldsoff);
      gload16(bb + brow1 + kk, (char*)sB[buf ^ 1] + 4096 + ldsoff);
    }
    bf16x8 av[4], bv[4];
#pragma unroll
    for (int f = 0; f < 4; ++f) {
      av[f] = *(const bf16x8*)&sA[buf][afrag + f * 512];
      bv[f] = *(const bf16x8*)&sB[buf][bfrag + f * 512];
    }
#pragma unroll
    for (int i = 0; i < 4; ++i)
#pragma unroll
      for (int j = 0; j < 4; ++j)
        acc[i][j] = __builtin_amdgcn_mfma_f32_16x16x32_bf16(av[i], bv[j], acc[i][j], 0, 0, 0);
  }

  // --- epilogue: 2 half-passes via [64][128] f32 LDS tile, 512B/row stores ---
  const int lc = lane & 15;
  const int lr4 = (lane >> 4) << 2;
  float b2v[4];
#pragma unroll
  for (int j = 0; j < 4; ++j) {
    const int c = n0 + wc + (j << 4) + lc;
    b2v[j] = eb2[(e << 10) + c] + ub2[c];
  }
  __syncthreads();
#pragma unroll
  for (int pass = 0; pass < 2; ++pass) {
    if ((wave >> 1) == pass) {
#pragma unroll
      for (int j = 0; j < 4; ++j) {
        const int c = wc + (j << 4) + lc;         // local col 0..127
#pragma unroll
        for (int i = 0; i < 4; ++i) {
          const int lrl = (i << 4) + lr4;          // local row 0..63
#pragma unroll
          for (int q = 0; q < 4; ++q)
            smemf[(lrl + q) * 128 + c] = acc[i][j][q] + b2v[j];
        }
      }
    }
    __syncthreads();
#pragma unroll
    for (int it = 0; it < 8; ++it) {
      const int lrl = (it << 3) + (wave << 1) + (lane >> 5);  // 0..63
      const int p = row0 + (pass << 6) + lrl;
      const float4 v = *(const float4*)&smemf[lrl * 128 + ((lane & 31) << 2)];
      if (p < gend)
        *(float4*)&out[((size_t)perm[p] << 10) + n0 + ((lane & 31) << 2)] = v;
    }
    __syncthreads();
  }
}

extern "C" void kernel_launch(void* const* d_in, const int* in_sizes, int n_in,
                              void* d_out, int out_size, void* d_ws, size_t ws_size,
                              hipStream_t stream) {
  const float* x   = (const float*)d_in[0];
  const float* ue  = (const float*)d_in[1];
  const float* sw1 = (const float*)d_in[2];
  const float* sb1 = (const float*)d_in[3];
  const float* sw2 = (const float*)d_in[4];
  const float* sb2 = (const float*)d_in[5];
  const float* ew1 = (const float*)d_in[6];
  const float* eb1 = (const float*)d_in[7];
  const float* ew2 = (const float*)d_in[8];
  const float* eb2 = (const float*)d_in[9];
  const float* uw1 = (const float*)d_in[10];
  const float* ub1 = (const float*)d_in[11];
  const float* uw2 = (const float*)d_in[12];
  const float* ub2 = (const float*)d_in[13];
  float* out = (float*)d_out;

  char* w = (char*)d_ws;
  int* meta = (int*)w;    w += 4096;
  int* routes = (int*)w;  w += NTOK * 4;
  int* perm = (int*)w;    w += NTOK * 4;
  char* region = w;
  u16* xg   = (u16*)region;                                             // 33,816,576 B
  u16* ew1t = (u16*)(region + 33816576ull);                             // 16 MiB
  u16* ew2t = (u16*)(region + 33816576ull + 16777216ull);               // 16 MiB
  u16* uw1t = (u16*)(region + 33816576ull + 2 * 16777216ull);           // 2 MiB
  u16* uw2t = (u16*)(region + 33816576ull + 2 * 16777216ull + 2097152ull);
  u16* hid  = (u16*)(region + 33816576ull + 2 * 16777216ull + 2 * 2097152ull);  // 67,633,152 B
  const size_t region_sz = 33816576ull + 2 * 16777216ull + 2 * 2097152ull + 67633152ull;
  // router-phase aliases live in the (dead-until-gemm1) hid region / xg region:
  _Float16* aP     = (_Float16*)(region + 33816576ull + 2 * 16777216ull + 2 * 2097152ull);
  float* hidden32  = (float*)region;
  _Float16* bP     = (_Float16*)(region + 16777216ull);
  if (135168ull + region_sz > ws_size) return;

  hipMemsetAsync(meta, 0, 4096, stream);
  prep_kernel<<<12864, 256, 0, stream>>>(ue, aP, sw1, bP, ew1, ew2, uw1, uw2,
                                         ew1t, ew2t, uw1t, uw2t);
  rgemm_kernel<<<512, 256, 0, stream>>>(aP, bP, sb1, hidden32);
  logits_kernel<<<NTOK / 128, 256, 0, stream>>>(hidden32, sw2, sb2, routes, meta);
  perm_kernel<<<NTOK / 256, 256, 0, stream>>>(routes, meta, perm);
  gatherx_kernel<<<(NTOK * 128) / 256, 256, 0, stream>>>(x, perm, xg);
  gemm1_kernel<<<2160, 256, 0, stream>>>(xg, ew1t, uw1t, eb1, ub1, meta, hid);
  gemm2_kernel<<<1080, 256, 0, stream>>>(hid, ew2t, uw2t, eb2, ub2, meta, perm, out);
}

// Round 16
// 339.788 us; speedup vs baseline: 1.8129x; 1.0397x over previous
//
#include <hip/hip_runtime.h>
#include <stdint.h>

#define NTOK 16384
#define HD   1024
#define SD   256
#define NE   8

typedef short bf16x8 __attribute__((ext_vector_type(8)));
typedef _Float16 f16x8 __attribute__((ext_vector_type(8)));
typedef float f32x4 __attribute__((ext_vector_type(4)));
typedef unsigned short u16;
typedef unsigned short u16x8 __attribute__((ext_vector_type(8)));

__device__ __forceinline__ u16 f2bf(float f) {
  union { float f; unsigned u; } v; v.f = f;
  return (u16)((v.u + 0x7fffu + ((v.u >> 16) & 1u)) >> 16);
}

__device__ __forceinline__ void gload16(const void* g, void* l) {
  __builtin_amdgcn_global_load_lds((const __attribute__((address_space(1))) void*)g,
                                   (__attribute__((address_space(3))) void*)l,
                                   16, 0, 0);
}

// meta layout (ints): [0..7] counts, [8..15] cursors, [16..24] offsets,
// [25] ntiles, [26] logits-done counter, [32..191] tile_e, [192..351] tile_row0,
// [352..511] tile_end

// LDS chunk-XOR swizzle (all GEMMs): conflict-free ds_read_b128, VMEM
// coalescing unchanged (verified: conflicts 8.7M -> 0). K-loops unrolled (r8).
// r11/r12: LDS-staged epilogues (WRITE_SIZE now exactly ideal on both GEMMs).
// r13/r14/r15: same-line atomic chains (perm 127us, logits 121us) fixed via
// two-level LDS counting -> -230us total.
// r16: tconv merged as TRAILING BLOCKS of the rgemm launch (no dependency on
// tconv output until gemm1) -> memory-bound tconv backfills CUs while the 512
// compute-bound rgemm blocks drain. rgemm path registers/LDS untouched (r12
// lesson); LDS is a 24KB union.
// r10: rgemm grid 512 (2 blocks/CU). r9: no atomic+barrier chains.

// ---------------- prep: aprep (8192 blk) + bprep (64 blk) ----------------
__global__ __launch_bounds__(256) void prep_kernel(
    const float* __restrict__ ue, _Float16* __restrict__ aP,
    const float* __restrict__ sw1, _Float16* __restrict__ bP) {
  const int bid = blockIdx.x;
  const int tid = threadIdx.x;
  if (bid < 8192) {
    // --- aprep: ue f32 -> A' = [hi | lo] fp16, row stride 2048 ---
    const int t = bid * 256 + tid;
    const int p = t >> 7;
    const int h = (t & 127) << 3;
    const float* s = ue + ((size_t)p << 10) + h;
    const float4 a = *(const float4*)s;
    const float4 b = *(const float4*)(s + 4);
    float v[8] = {a.x, a.y, a.z, a.w, b.x, b.y, b.z, b.w};
    f16x8 hi, lo;
#pragma unroll
    for (int j = 0; j < 8; ++j) {
      const _Float16 h16 = (_Float16)v[j];
      hi[j] = h16;
      lo[j] = (_Float16)(v[j] - (float)h16);
    }
    _Float16* d = aP + ((size_t)p << 11) + h;
    *(f16x8*)d = hi;
    *(f16x8*)(d + 1024) = lo;
    return;
  }
  // --- bprep: sw1 [1024][256] f32 -> B' [256][3072] fp16 = [hi|lo|hi] ---
  __shared__ float tb[64][65];
  const int b = bid - 8192;
  const int c0 = (b & 3) << 6;
  const int r0 = (b >> 2) << 6;
  {
    const int lr = tid >> 2, q = (tid & 3) << 4;
    const float* s = sw1 + (size_t)(r0 + lr) * SD + c0 + q;
#pragma unroll
    for (int j = 0; j < 16; j += 4) {
      const float4 v = *(const float4*)(s + j);
      tb[lr][q + j] = v.x; tb[lr][q + j + 1] = v.y;
      tb[lr][q + j + 2] = v.z; tb[lr][q + j + 3] = v.w;
    }
  }
  __syncthreads();
  const int lc = tid >> 2, rq = (tid & 3) << 4;
  f16x8 hi0, hi1, lo0, lo1;
#pragma unroll
  for (int j = 0; j < 8; ++j) {
    const float v0 = tb[rq + j][lc];
    const _Float16 h0 = (_Float16)v0;
    hi0[j] = h0; lo0[j] = (_Float16)(v0 - (float)h0);
    const float v1 = tb[rq + 8 + j][lc];
    const _Float16 h1 = (_Float16)v1;
    hi1[j] = h1; lo1[j] = (_Float16)(v1 - (float)h1);
  }
  _Float16* d = bP + (size_t)(c0 + lc) * 3072 + r0 + rq;
  *(f16x8*)d = hi0;           *(f16x8*)(d + 8) = hi1;
  *(f16x8*)(d + 1024) = lo0;  *(f16x8*)(d + 1032) = lo1;
  *(f16x8*)(d + 2048) = hi0;  *(f16x8*)(d + 2056) = hi1;
}

// ---------------- rgemm (blocks 0..511) + tconv (blocks 512..5119) ----------------
// rgemm: hidden[p][s] = relu(3-term hi/lo fp16 MFMA + sb1), f32 out.
// tconv: transpose+convert 1024x1024 f32 -> bf16, 18 matrices (no consumer
// until gemm1 -> overlaps rgemm on idle CUs).
__global__ __launch_bounds__(256) void rtconv_kernel(
    const _Float16* __restrict__ aP, const _Float16* __restrict__ bP,
    const float* __restrict__ sb1, float* __restrict__ hidden,
    const float* __restrict__ ew1, const float* __restrict__ ew2,
    const float* __restrict__ uw1, const float* __restrict__ uw2,
    u16* __restrict__ ew1t, u16* __restrict__ ew2t,
    u16* __restrict__ uw1t, u16* __restrict__ uw2t) {
  __shared__ char smem[24576];   // union: rgemm sA(16K)+sB(8K) | tconv tb(16.6K)
  const int bid = blockIdx.x;
  const int tid = threadIdx.x;

  if (bid < 512) {
    _Float16 (*sA)[128 * 32] = (_Float16(*)[128 * 32])smem;
    _Float16 (*sB)[64 * 32]  = (_Float16(*)[64 * 32])(smem + 16384);

    const int L = (bid & 7) * 64 + (bid >> 3);
    const int jt = L & 3;           // 64-col tile
    const int row0 = (L >> 2) << 7; // 128-row tile

    const int lane = tid & 63, wave = tid >> 6;
    const int wr = (wave >> 1) << 6, wc = (wave & 1) << 5;
    const int smrow = tid >> 2, skoff = (((tid & 3) ^ ((tid >> 3) & 3)) << 3);
    const _Float16* ar0 = aP + ((size_t)(row0 + smrow) << 11) + skoff;
    const _Float16* ar1 = aP + ((size_t)(row0 + smrow + 64) << 11) + skoff;
    const _Float16* br  = bP + (size_t)((jt << 6) + smrow) * 3072 + skoff;
    const int ldsoff = wave << 10;

    f32x4 acc[4][2];
#pragma unroll
    for (int i = 0; i < 4; ++i)
#pragma unroll
      for (int j = 0; j < 2; ++j) acc[i][j] = (f32x4){0.f, 0.f, 0.f, 0.f};

    gload16(ar0, (char*)sA[0] + ldsoff);
    gload16(ar1, (char*)sA[0] + 4096 + ldsoff);
    gload16(br,  (char*)sB[0] + ldsoff);

    const int sl = (((lane >> 4) ^ ((lane >> 1) & 3)) << 3);
    const int afrag = (wr + (lane & 15)) * 32 + sl;
    const int bfrag = (wc + (lane & 15)) * 32 + sl;

#pragma unroll
    for (int ks = 0; ks < 96; ++ks) {
      const int buf = ks & 1;
      __syncthreads();
      if (ks + 1 < 96) {
        const int k1 = ks + 1;
        const int pa = (k1 < 64) ? ((k1 & 31) << 5) : (1024 + ((k1 - 64) << 5));
        gload16(ar0 + pa, (char*)sA[buf ^ 1] + ldsoff);
        gload16(ar1 + pa, (char*)sA[buf ^ 1] + 4096 + ldsoff);
        gload16(br + (k1 << 5), (char*)sB[buf ^ 1] + ldsoff);
      }
      f16x8 av[4], bv[2];
#pragma unroll
      for (int f = 0; f < 4; ++f) av[f] = *(const f16x8*)&sA[buf][afrag + f * 512];
#pragma unroll
      for (int f = 0; f < 2; ++f) bv[f] = *(const f16x8*)&sB[buf][bfrag + f * 512];
#pragma unroll
      for (int i = 0; i < 4; ++i)
#pragma unroll
        for (int j = 0; j < 2; ++j)
          acc[i][j] = __builtin_amdgcn_mfma_f32_16x16x32_f16(av[i], bv[j], acc[i][j], 0, 0, 0);
    }

    const int lc = lane & 15, lr4 = (lane >> 4) << 2;
#pragma unroll
    for (int j = 0; j < 2; ++j) {
      const int c = (jt << 6) + wc + (j << 4) + lc;
      const float bias = sb1[c];
#pragma unroll
      for (int i = 0; i < 4; ++i) {
        const int rl = wr + (i << 4) + lr4;
#pragma unroll
        for (int q = 0; q < 4; ++q)
          hidden[((size_t)(row0 + rl + q) << 8) + c] = fmaxf(acc[i][j][q] + bias, 0.f);
      }
    }
    return;
  }

  // --- tconv ---
  float (*tb)[65] = (float(*)[65])smem;
  const int c = bid - 512;
  const int m = c >> 8;
  const int t2 = c & 255;
  const int c0 = (t2 & 15) << 6;
  const int r0 = (t2 >> 4) << 6;
  const size_t msz = (size_t)HD * HD;
  const float* src; u16* dst;
  if (m < 8)       { src = ew1 + (size_t)m * msz;       dst = ew1t + (size_t)m * msz; }
  else if (m < 16) { src = ew2 + (size_t)(m - 8) * msz; dst = ew2t + (size_t)(m - 8) * msz; }
  else if (m == 16){ src = uw1;                          dst = uw1t; }
  else             { src = uw2;                          dst = uw2t; }
  {
    const int lr = tid >> 2, q = (tid & 3) << 4;
    const float* s = src + (size_t)(r0 + lr) * HD + c0 + q;
#pragma unroll
    for (int j = 0; j < 16; j += 4) {
      const float4 v = *(const float4*)(s + j);
      tb[lr][q + j] = v.x; tb[lr][q + j + 1] = v.y;
      tb[lr][q + j + 2] = v.z; tb[lr][q + j + 3] = v.w;
    }
  }
  __syncthreads();
  {
    const int lc = tid >> 2, rq = (tid & 3) << 4;
    u16x8 o0, o1;
#pragma unroll
    for (int j = 0; j < 8; ++j) o0[j] = f2bf(tb[rq + j][lc]);
#pragma unroll
    for (int j = 0; j < 8; ++j) o1[j] = f2bf(tb[rq + 8 + j][lc]);
    u16* d = dst + (size_t)(c0 + lc) * HD + r0 + rq;
    *(u16x8*)d = o0;
    *(u16x8*)(d + 8) = o1;
  }
}

// ---------------- Logits: 128 tok/block, LDS histogram (r15), fused scan ----------------
__global__ __launch_bounds__(256) void logits_kernel(
    const float* __restrict__ hidden, const float* __restrict__ sw2,
    const float* __restrict__ sb2, int* __restrict__ routes, int* meta) {
  __shared__ float logl[32][8];
  __shared__ int lhist[NE];
  const int tid = threadIdx.x;
  if (tid < NE) lhist[tid] = 0;
  const int tok0 = blockIdx.x << 7;     // 128 tokens per block
  const int tl = tid >> 3, e2 = tid & 7;
  __syncthreads();
#pragma unroll 1
  for (int g4 = 0; g4 < 4; ++g4) {
    const float* hp = hidden + ((size_t)(tok0 + (g4 << 5) + tl) << 8);
    float a0 = 0.f, a1 = 0.f, a2 = 0.f, a3 = 0.f;
    for (int q = 0; q < SD; q += 8) {
      const float4 h0 = *(const float4*)&hp[q];
      const float4 h1 = *(const float4*)&hp[q + 4];
      a0 = fmaf(h0.x, sw2[((q + 0) << 3) + e2], a0);
      a1 = fmaf(h0.y, sw2[((q + 1) << 3) + e2], a1);
      a2 = fmaf(h0.z, sw2[((q + 2) << 3) + e2], a2);
      a3 = fmaf(h0.w, sw2[((q + 3) << 3) + e2], a3);
      a0 = fmaf(h1.x, sw2[((q + 4) << 3) + e2], a0);
      a1 = fmaf(h1.y, sw2[((q + 5) << 3) + e2], a1);
      a2 = fmaf(h1.z, sw2[((q + 6) << 3) + e2], a2);
      a3 = fmaf(h1.w, sw2[((q + 7) << 3) + e2], a3);
    }
    logl[tl][e2] = (a0 + a1) + (a2 + a3) + sb2[e2];
    __syncthreads();
    if (tid < 32) {
      float best = logl[tid][0]; int be = 0;
#pragma unroll
      for (int e = 1; e < 8; ++e) {
        const float v = logl[tid][e];
        if (v > best) { best = v; be = e; }
      }
      routes[tok0 + (g4 << 5) + tid] = be;
      atomicAdd(&lhist[be], 1);
    }
    __syncthreads();
  }
  if (tid < NE) atomicAdd(&meta[tid], lhist[tid]);
  __syncthreads();
  if (tid == 0) {
    __threadfence();
    const int done = atomicAdd(&meta[26], 1);
    if (done == (int)gridDim.x - 1) {
      int cnt[NE];
#pragma unroll
      for (int e = 0; e < NE; ++e) cnt[e] = atomicAdd(&meta[e], 0);
      int off = 0;
      for (int e = 0; e < NE; ++e) { meta[16 + e] = off; off += cnt[e]; }
      meta[24] = off;
      int nt = 0;
      for (int e = 0; e < NE; ++e) {
        const int s = meta[16 + e], en = meta[16 + e + 1];
        for (int r0 = s; r0 < en; r0 += 128) {
          meta[32 + nt] = e; meta[192 + nt] = r0; meta[352 + nt] = en; ++nt;
        }
      }
      meta[25] = nt;
      __threadfence();
    }
  }
}

// ---------------- Build permutation: two-level counting (r13) ----------------
__global__ __launch_bounds__(256) void perm_kernel(
    const int* __restrict__ routes, int* meta, int* __restrict__ perm) {
  __shared__ int lcnt[NE], lbase[NE], lcur[NE];
  const int tid = threadIdx.x;
  if (tid < NE) { lcnt[tid] = 0; lcur[tid] = 0; }
  __syncthreads();
  const int b = blockIdx.x * 256 + tid;
  const int r = routes[b];
  atomicAdd(&lcnt[r], 1);
  __syncthreads();
  if (tid < NE)
    lbase[tid] = meta[16 + tid] + atomicAdd(&meta[8 + tid], lcnt[tid]);
  __syncthreads();
  const int rank = atomicAdd(&lcur[r], 1);
  perm[lbase[r] + rank] = b;
}

// ---------------- Gather x rows into grouped order, f32 -> bf16 ----------------
__global__ __launch_bounds__(256) void gatherx_kernel(
    const float* __restrict__ x, const int* __restrict__ perm, u16* __restrict__ xg) {
  const int t = blockIdx.x * 256 + threadIdx.x;
  const int p = t >> 7;
  const int j = (t & 127) << 3;
  const int tok = perm[p];
  const float* s = &x[((size_t)tok << 10) + j];
  const float4 a = *(const float4*)s;
  const float4 b = *(const float4*)(s + 4);
  u16x8 o;
  o[0] = f2bf(a.x); o[1] = f2bf(a.y); o[2] = f2bf(a.z); o[3] = f2bf(a.w);
  o[4] = f2bf(b.x); o[5] = f2bf(b.y); o[6] = f2bf(b.z); o[7] = f2bf(b.w);
  *(u16x8*)&xg[((size_t)p << 10) + j] = o;
}

// ---------------- GEMM1: hid[p][0:2048] = relu(xg[p] @ [ew1[e] | uw1] + eb1[e]/ub1) ----------------
__global__ __launch_bounds__(256) void gemm1_kernel(
    const u16* __restrict__ xg, const u16* __restrict__ ew1t,
    const u16* __restrict__ uw1t, const float* __restrict__ eb1,
    const float* __restrict__ ub1, const int* __restrict__ meta,
    u16* __restrict__ hid) {
  const int nt = meta[25];
  // XCD-chunked, mt-major: grid 2160 = 16 jt x 135 mt
  const int pb = blockIdx.x;
  const int L = (pb & 7) * 270 + (pb >> 3);
  const int mt = L >> 4;
  const int jt = L & 15;
  if (mt >= nt) return;
  const int e = meta[32 + mt], row0 = meta[192 + mt], gend = meta[352 + mt];
  const u16* wbase = (jt < 8)
      ? ew1t + ((size_t)e << 20) + ((size_t)(jt << 7) << 10)
      : uw1t + ((size_t)((jt - 8) << 7) << 10);

  // 32KB unified LDS: K-loop sA/sB; epilogue reuses as [128][128] u16 tile.
  __shared__ u16 smem[16384];
  u16 (*sA)[4096] = (u16(*)[4096])smem;
  u16 (*sB)[4096] = (u16(*)[4096])(smem + 8192);

  const int tid = threadIdx.x;
  const int lane = tid & 63;
  const int wave = tid >> 6;
  const int wr = (wave >> 1) << 6;
  const int wc = (wave & 1) << 6;

  const int smrow = tid >> 2;
  const int skoff = (((tid & 3) ^ ((tid >> 3) & 3)) << 3);
  const u16* ap0 = xg + (((size_t)(row0 + smrow)) << 10) + skoff;
  const u16* ap1 = xg + (((size_t)(row0 + smrow + 64)) << 10) + skoff;
  const u16* bp0 = wbase + (((size_t)smrow) << 10) + skoff;
  const u16* bp1 = wbase + (((size_t)(smrow + 64)) << 10) + skoff;
  const int ldsoff = wave << 10;

  f32x4 acc[4][4];
#pragma unroll
  for (int i = 0; i < 4; ++i)
#pragma unroll
    for (int j = 0; j < 4; ++j) acc[i][j] = (f32x4){0.f, 0.f, 0.f, 0.f};

  gload16(ap0, (char*)sA[0] + ldsoff);
  gload16(ap1, (char*)sA[0] + 4096 + ldsoff);
  gload16(bp0, (char*)sB[0] + ldsoff);
  gload16(bp1, (char*)sB[0] + 4096 + ldsoff);

  const int sl = (((lane >> 4) ^ ((lane >> 1) & 3)) << 3);
  const int afrag = (wr + (lane & 15)) * 32 + sl;
  const int bfrag = (wc + (lane & 15)) * 32 + sl;

#pragma unroll
  for (int ks = 0; ks < 32; ++ks) {
    const int buf = ks & 1;
    __syncthreads();
    if (ks + 1 < 32) {
      const int k1 = (ks + 1) << 5;
      gload16(ap0 + k1, (char*)sA[buf ^ 1] + ldsoff);
      gload16(ap1 + k1, (char*)sA[buf ^ 1] + 4096 + ldsoff);
      gload16(bp0 + k1, (char*)sB[buf ^ 1] + ldsoff);
      gload16(bp1 + k1, (char*)sB[buf ^ 1] + 4096 + ldsoff);
    }
    bf16x8 av[4], bv[4];
#pragma unroll
    for (int f = 0; f < 4; ++f) {
      av[f] = *(const bf16x8*)&sA[buf][afrag + f * 512];
      bv[f] = *(const bf16x8*)&sB[buf][bfrag + f * 512];
    }
#pragma unroll
    for (int i = 0; i < 4; ++i)
#pragma unroll
      for (int j = 0; j < 4; ++j)
        acc[i][j] = __builtin_amdgcn_mfma_f32_16x16x32_bf16(av[i], bv[j], acc[i][j], 0, 0, 0);
  }

  // --- epilogue: bias+relu+cvt -> LDS tile, then 256B-contiguous stores ---
  __syncthreads();
  {
    const int lc = lane & 15;
    const int lr4 = (lane >> 4) << 2;
#pragma unroll
    for (int j = 0; j < 4; ++j) {
      const int c = wc + (j << 4) + lc;           // local col 0..127
      const int gc = (jt << 7) + c;
      const float bias = (gc < 1024) ? eb1[(e << 10) + gc] : ub1[gc - 1024];
#pragma unroll
      for (int i = 0; i < 4; ++i) {
        const int rl = wr + (i << 4) + lr4;
#pragma unroll
        for (int q = 0; q < 4; ++q)
          smem[(rl + q) * 128 + c] = f2bf(fmaxf(acc[i][j][q] + bias, 0.f));
      }
    }
  }
  __syncthreads();
  {
    const int l16 = lane & 15, rg = lane >> 4;
#pragma unroll
    for (int it = 0; it < 8; ++it) {
      const int lr = (wave << 5) + (it << 2) + rg;   // local row 0..127
      const int p = row0 + lr;
      const u16x8 v = *(const u16x8*)&smem[lr * 128 + (l16 << 3)];
      if (p < gend)
        *(u16x8*)&hid[((size_t)p << 11) + (jt << 7) + (l16 << 3)] = v;
    }
  }
}

// ---------------- GEMM2: out[perm[p]][c] = hid[p] @ [ew2[e]; uw2] + eb2[e] + ub2 ----------------
__global__ __launch_bounds__(256) void gemm2_kernel(
    const u16* __restrict__ hid, const u16* __restrict__ ew2t,
    const u16* __restrict__ uw2t, const float* __restrict__ eb2,
    const float* __restrict__ ub2, const int* __restrict__ meta,
    const int* __restrict__ perm, float* __restrict__ out) {
  const int nt = meta[25];
  // XCD-chunked, mt-major: grid 1080 = 8 jt x 135 mt
  const int pb = blockIdx.x;
  const int L = (pb & 7) * 135 + (pb >> 3);
  const int mt = L >> 3;
  const int jt = L & 7;
  if (mt >= nt) return;
  const int e = meta[32 + mt], row0 = meta[192 + mt], gend = meta[352 + mt];
  const int n0 = jt << 7;

  // 32KB unified LDS: K-loop sA/sB; epilogue reuses as [64][128] f32 half-tile.
  __shared__ u16 smem[16384];
  u16 (*sA)[4096] = (u16(*)[4096])smem;
  u16 (*sB)[4096] = (u16(*)[4096])(smem + 8192);
  float* smemf = (float*)smem;

  const int tid = threadIdx.x;
  const int lane = tid & 63;
  const int wave = tid >> 6;
  const int wr = (wave >> 1) << 6;
  const int wc = (wave & 1) << 6;

  const int smrow = tid >> 2;
  const int skoff = (((tid & 3) ^ ((tid >> 3) & 3)) << 3);
  const u16* ap0 = hid + (((size_t)(row0 + smrow)) << 11) + skoff;
  const u16* ap1 = hid + (((size_t)(row0 + smrow + 64)) << 11) + skoff;
  const u16* ebase = ew2t + ((size_t)e << 20);
  const size_t brow0 = (((size_t)(n0 + smrow)) << 10) + skoff;
  const size_t brow1 = (((size_t)(n0 + smrow + 64)) << 10) + skoff;
  const int ldsoff = wave << 10;

  f32x4 acc[4][4];
#pragma unroll
  for (int i = 0; i < 4; ++i)
#pragma unroll
    for (int j = 0; j < 4; ++j) acc[i][j] = (f32x4){0.f, 0.f, 0.f, 0.f};

  gload16(ap0, (char*)sA[0] + ldsoff);
  gload16(ap1, (char*)sA[0] + 4096 + ldsoff);
  gload16(ebase + brow0, (char*)sB[0] + ldsoff);
  gload16(ebase + brow1, (char*)sB[0] + 4096 + ldsoff);

  const int sl = (((lane >> 4) ^ ((lane >> 1) & 3)) << 3);
  const int afrag = (wr + (lane & 15)) * 32 + sl;
  const int bfrag = (wc + (lane & 15)) * 32 + sl;

#pragma unroll
  for (int ks = 0; ks < 64; ++ks) {
    const int buf = ks & 1;
    __syncthreads();
    if (ks + 1 < 64) {
      const int k1 = (ks + 1) << 5;
      const u16* bb = (k1 < 1024) ? ebase : uw2t;
      const int kk = k1 & 1023;
      gload16(ap0 + k1, (char*)sA[buf ^ 1] + ldsoff);
      gload16(ap1 + k1, (char*)sA[buf ^ 1] + 4096 + ldsoff);
      gload16(bb + brow0 + kk, (char*)sB[buf ^ 1] + ldsoff);
      gload16(bb + brow1 + kk, (char*)sB[buf ^ 1] + 4096 + ldsoff);
    }
    bf16x8 av[4], bv[4];
#pragma unroll
    for (int f = 0; f < 4; ++f) {
      av[f] = *(const bf16x8*)&sA[buf][afrag + f * 512];
      bv[f] = *(const bf16x8*)&sB[buf][bfrag + f * 512];
    }
#pragma unroll
    for (int i = 0; i < 4; ++i)
#pragma unroll
      for (int j = 0; j < 4; ++j)
        acc[i][j] = __builtin_amdgcn_mfma_f32_16x16x32_bf16(av[i], bv[j], acc[i][j], 0, 0, 0);
  }

  // --- epilogue: 2 half-passes via [64][128] f32 LDS tile, 512B/row stores ---
  const int lc = lane & 15;
  const int lr4 = (lane >> 4) << 2;
  float b2v[4];
#pragma unroll
  for (int j = 0; j < 4; ++j) {
    const int c = n0 + wc + (j << 4) + lc;
    b2v[j] = eb2[(e << 10) + c] + ub2[c];
  }
  __syncthreads();
#pragma unroll
  for (int pass = 0; pass < 2; ++pass) {
    if ((wave >> 1) == pass) {
#pragma unroll
      for (int j = 0; j < 4; ++j) {
        const int c = wc + (j << 4) + lc;         // local col 0..127
#pragma unroll
        for (int i = 0; i < 4; ++i) {
          const int lrl = (i << 4) + lr4;          // local row 0..63
#pragma unroll
          for (int q = 0; q < 4; ++q)
            smemf[(lrl + q) * 128 + c] = acc[i][j][q] + b2v[j];
        }
      }
    }
    __syncthreads();
#pragma unroll
    for (int it = 0; it < 8; ++it) {
      const int lrl = (it << 3) + (wave << 1) + (lane >> 5);  // 0..63
      const int p = row0 + (pass << 6) + lrl;
      const float4 v = *(const float4*)&smemf[lrl * 128 + ((lane & 31) << 2)];
      if (p < gend)
        *(float4*)&out[((size_t)perm[p] << 10) + n0 + ((lane & 31) << 2)] = v;
    }
    __syncthreads();
  }
}

extern "C" void kernel_launch(void* const* d_in, const int* in_sizes, int n_in,
                              void* d_out, int out_size, void* d_ws, size_t ws_size,
                              hipStream_t stream) {
  const float* x   = (const float*)d_in[0];
  const float* ue  = (const float*)d_in[1];
  const float* sw1 = (const float*)d_in[2];
  const float* sb1 = (const float*)d_in[3];
  const float* sw2 = (const float*)d_in[4];
  const float* sb2 = (const float*)d_in[5];
  const float* ew1 = (const float*)d_in[6];
  const float* eb1 = (const float*)d_in[7];
  const float* ew2 = (const float*)d_in[8];
  const float* eb2 = (const float*)d_in[9];
  const float* uw1 = (const float*)d_in[10];
  const float* ub1 = (const float*)d_in[11];
  const float* uw2 = (const float*)d_in[12];
  const float* ub2 = (const float*)d_in[13];
  float* out = (float*)d_out;

  char* w = (char*)d_ws;
  int* meta = (int*)w;    w += 4096;
  int* routes = (int*)w;  w += NTOK * 4;
  int* perm = (int*)w;    w += NTOK * 4;
  char* region = w;
  u16* xg   = (u16*)region;                                             // 33,816,576 B
  u16* ew1t = (u16*)(region + 33816576ull);                             // 16 MiB
  u16* ew2t = (u16*)(region + 33816576ull + 16777216ull);               // 16 MiB
  u16* uw1t = (u16*)(region + 33816576ull + 2 * 16777216ull);           // 2 MiB
  u16* uw2t = (u16*)(region + 33816576ull + 2 * 16777216ull + 2097152ull);
  u16* hid  = (u16*)(region + 33816576ull + 2 * 16777216ull + 2 * 2097152ull);  // 67,633,152 B
  const size_t region_sz = 33816576ull + 2 * 16777216ull + 2 * 2097152ull + 67633152ull;
  // router-phase aliases live in the (dead-until-gemm1) hid region / xg region:
  _Float16* aP     = (_Float16*)(region + 33816576ull + 2 * 16777216ull + 2 * 2097152ull);
  float* hidden32  = (float*)region;
  _Float16* bP     = (_Float16*)(region + 16777216ull);
  if (135168ull + region_sz > ws_size) return;

  hipMemsetAsync(meta, 0, 4096, stream);
  prep_kernel<<<8256, 256, 0, stream>>>(ue, aP, sw1, bP);
  rtconv_kernel<<<5120, 256, 0, stream>>>(aP, bP, sb1, hidden32,
                                          ew1, ew2, uw1, uw2,
                                          ew1t, ew2t, uw1t, uw2t);
  logits_kernel<<<NTOK / 128, 256, 0, stream>>>(hidden32, sw2, sb2, routes, meta);
  perm_kernel<<<NTOK / 256, 256, 0, stream>>>(routes, meta, perm);
  gatherx_kernel<<<(NTOK * 128) / 256, 256, 0, stream>>>(x, perm, xg);
  gemm1_kernel<<<2160, 256, 0, stream>>>(xg, ew1t, uw1t, eb1, ub1, meta, hid);
  gemm2_kernel<<<1080, 256, 0, stream>>>(hid, ew2t, uw2t, eb2, ub2, meta, perm, out);
}

// Round 17
// 333.557 us; speedup vs baseline: 1.8467x; 1.0187x over previous
//
#include <hip/hip_runtime.h>
#include <stdint.h>

#define NTOK 16384
#define HD   1024
#define SD   256
#define NE   8

typedef short bf16x8 __attribute__((ext_vector_type(8)));
typedef _Float16 f16x8 __attribute__((ext_vector_type(8)));
typedef float f32x4 __attribute__((ext_vector_type(4)));
typedef unsigned short u16;
typedef unsigned short u16x8 __attribute__((ext_vector_type(8)));

__device__ __forceinline__ u16 f2bf(float f) {
  union { float f; unsigned u; } v; v.f = f;
  return (u16)((v.u + 0x7fffu + ((v.u >> 16) & 1u)) >> 16);
}

__device__ __forceinline__ void gload16(const void* g, void* l) {
  __builtin_amdgcn_global_load_lds((const __attribute__((address_space(1))) void*)g,
                                   (__attribute__((address_space(3))) void*)l,
                                   16, 0, 0);
}

__device__ __forceinline__ void xcvt_rows(const float* __restrict__ x,
                                          u16* __restrict__ xg,
                                          int row_base, int blk, int tid) {
  // 2 rows per 256-thread block, token order (no gather)
  const int t = blk * 256 + tid;
  const int p = row_base + (t >> 7);
  const int j = (t & 127) << 3;
  const float* s = &x[((size_t)p << 10) + j];
  const float4 a = *(const float4*)s;
  const float4 b = *(const float4*)(s + 4);
  u16x8 o;
  o[0] = f2bf(a.x); o[1] = f2bf(a.y); o[2] = f2bf(a.z); o[3] = f2bf(a.w);
  o[4] = f2bf(b.x); o[5] = f2bf(b.y); o[6] = f2bf(b.z); o[7] = f2bf(b.w);
  *(u16x8*)&xg[((size_t)p << 10) + j] = o;
}

// meta layout (ints): [0..7] counts, [8..15] cursors, [16..24] offsets,
// [25] ntiles, [26] logits-done counter, [32..191] tile_e, [192..351] tile_row0,
// [352..511] tile_end

// LDS chunk-XOR swizzle (all GEMMs): conflict-free ds_read_b128, VMEM
// coalescing unchanged (conflicts 8.7M -> 0). K-loops unrolled (r8).
// r11/r12: LDS-staged epilogues (WRITE_SIZE exactly ideal both GEMMs).
// r13-r15: same-line atomic chains fixed via two-level LDS counting (-230us).
// r16: tconv as trailing blocks of rgemm launch (-13.5us).
// r17: gatherx ELIMINATED -- xg written in TOKEN order (route-free), gemm1
// indirects A rows through perm[] at setup (hot loop untouched; 64B/row
// coalescing per 4-lane group unchanged). Aliasing-exact split: xg rows
// 8960..16383 convert inside rtconv (overlap rgemm); rows 0..8959 (under
// hidden32[rows 0..8191] + bP[rows 8192..8959]) convert as trailing blocks
// of perm (hidden32/bP dead there).
// r12: no fusion that grows hot-GEMM VGPR/LDS. r10: rgemm grid 512.
// r9: no per-token atomic+barrier chains.

// ---------------- prep: aprep (8192 blk) + bprep (64 blk) ----------------
__global__ __launch_bounds__(256) void prep_kernel(
    const float* __restrict__ ue, _Float16* __restrict__ aP,
    const float* __restrict__ sw1, _Float16* __restrict__ bP) {
  const int bid = blockIdx.x;
  const int tid = threadIdx.x;
  if (bid < 8192) {
    // --- aprep: ue f32 -> A' = [hi | lo] fp16, row stride 2048 ---
    const int t = bid * 256 + tid;
    const int p = t >> 7;
    const int h = (t & 127) << 3;
    const float* s = ue + ((size_t)p << 10) + h;
    const float4 a = *(const float4*)s;
    const float4 b = *(const float4*)(s + 4);
    float v[8] = {a.x, a.y, a.z, a.w, b.x, b.y, b.z, b.w};
    f16x8 hi, lo;
#pragma unroll
    for (int j = 0; j < 8; ++j) {
      const _Float16 h16 = (_Float16)v[j];
      hi[j] = h16;
      lo[j] = (_Float16)(v[j] - (float)h16);
    }
    _Float16* d = aP + ((size_t)p << 11) + h;
    *(f16x8*)d = hi;
    *(f16x8*)(d + 1024) = lo;
    return;
  }
  // --- bprep: sw1 [1024][256] f32 -> B' [256][3072] fp16 = [hi|lo|hi] ---
  __shared__ float tb[64][65];
  const int b = bid - 8192;
  const int c0 = (b & 3) << 6;
  const int r0 = (b >> 2) << 6;
  {
    const int lr = tid >> 2, q = (tid & 3) << 4;
    const float* s = sw1 + (size_t)(r0 + lr) * SD + c0 + q;
#pragma unroll
    for (int j = 0; j < 16; j += 4) {
      const float4 v = *(const float4*)(s + j);
      tb[lr][q + j] = v.x; tb[lr][q + j + 1] = v.y;
      tb[lr][q + j + 2] = v.z; tb[lr][q + j + 3] = v.w;
    }
  }
  __syncthreads();
  const int lc = tid >> 2, rq = (tid & 3) << 4;
  f16x8 hi0, hi1, lo0, lo1;
#pragma unroll
  for (int j = 0; j < 8; ++j) {
    const float v0 = tb[rq + j][lc];
    const _Float16 h0 = (_Float16)v0;
    hi0[j] = h0; lo0[j] = (_Float16)(v0 - (float)h0);
    const float v1 = tb[rq + 8 + j][lc];
    const _Float16 h1 = (_Float16)v1;
    hi1[j] = h1; lo1[j] = (_Float16)(v1 - (float)h1);
  }
  _Float16* d = bP + (size_t)(c0 + lc) * 3072 + r0 + rq;
  *(f16x8*)d = hi0;           *(f16x8*)(d + 8) = hi1;
  *(f16x8*)(d + 1024) = lo0;  *(f16x8*)(d + 1032) = lo1;
  *(f16x8*)(d + 2048) = hi0;  *(f16x8*)(d + 2056) = hi1;
}

// ------- rtconv: rgemm (0..511) + tconv (512..5119) + xcvt rows 8960+ (5120..8831) -------
__global__ __launch_bounds__(256) void rtconv_kernel(
    const _Float16* __restrict__ aP, const _Float16* __restrict__ bP,
    const float* __restrict__ sb1, float* __restrict__ hidden,
    const float* __restrict__ ew1, const float* __restrict__ ew2,
    const float* __restrict__ uw1, const float* __restrict__ uw2,
    u16* __restrict__ ew1t, u16* __restrict__ ew2t,
    u16* __restrict__ uw1t, u16* __restrict__ uw2t,
    const float* __restrict__ x, u16* __restrict__ xg) {
  __shared__ char smem[24576];   // union: rgemm sA(16K)+sB(8K) | tconv tb(16.6K)
  const int bid = blockIdx.x;
  const int tid = threadIdx.x;

  if (bid >= 5120) {
    // --- xcvt: tokens 8960..16383 (above hidden32+bP alias region) ---
    xcvt_rows(x, xg, 8960, bid - 5120, tid);
    return;
  }
  if (bid < 512) {
    _Float16 (*sA)[128 * 32] = (_Float16(*)[128 * 32])smem;
    _Float16 (*sB)[64 * 32]  = (_Float16(*)[64 * 32])(smem + 16384);

    const int L = (bid & 7) * 64 + (bid >> 3);
    const int jt = L & 3;           // 64-col tile
    const int row0 = (L >> 2) << 7; // 128-row tile

    const int lane = tid & 63, wave = tid >> 6;
    const int wr = (wave >> 1) << 6, wc = (wave & 1) << 5;
    const int smrow = tid >> 2, skoff = (((tid & 3) ^ ((tid >> 3) & 3)) << 3);
    const _Float16* ar0 = aP + ((size_t)(row0 + smrow) << 11) + skoff;
    const _Float16* ar1 = aP + ((size_t)(row0 + smrow + 64) << 11) + skoff;
    const _Float16* br  = bP + (size_t)((jt << 6) + smrow) * 3072 + skoff;
    const int ldsoff = wave << 10;

    f32x4 acc[4][2];
#pragma unroll
    for (int i = 0; i < 4; ++i)
#pragma unroll
      for (int j = 0; j < 2; ++j) acc[i][j] = (f32x4){0.f, 0.f, 0.f, 0.f};

    gload16(ar0, (char*)sA[0] + ldsoff);
    gload16(ar1, (char*)sA[0] + 4096 + ldsoff);
    gload16(br,  (char*)sB[0] + ldsoff);

    const int sl = (((lane >> 4) ^ ((lane >> 1) & 3)) << 3);
    const int afrag = (wr + (lane & 15)) * 32 + sl;
    const int bfrag = (wc + (lane & 15)) * 32 + sl;

#pragma unroll
    for (int ks = 0; ks < 96; ++ks) {
      const int buf = ks & 1;
      __syncthreads();
      if (ks + 1 < 96) {
        const int k1 = ks + 1;
        const int pa = (k1 < 64) ? ((k1 & 31) << 5) : (1024 + ((k1 - 64) << 5));
        gload16(ar0 + pa, (char*)sA[buf ^ 1] + ldsoff);
        gload16(ar1 + pa, (char*)sA[buf ^ 1] + 4096 + ldsoff);
        gload16(br + (k1 << 5), (char*)sB[buf ^ 1] + ldsoff);
      }
      f16x8 av[4], bv[2];
#pragma unroll
      for (int f = 0; f < 4; ++f) av[f] = *(const f16x8*)&sA[buf][afrag + f * 512];
#pragma unroll
      for (int f = 0; f < 2; ++f) bv[f] = *(const f16x8*)&sB[buf][bfrag + f * 512];
#pragma unroll
      for (int i = 0; i < 4; ++i)
#pragma unroll
        for (int j = 0; j < 2; ++j)
          acc[i][j] = __builtin_amdgcn_mfma_f32_16x16x32_f16(av[i], bv[j], acc[i][j], 0, 0, 0);
    }

    const int lc = lane & 15, lr4 = (lane >> 4) << 2;
#pragma unroll
    for (int j = 0; j < 2; ++j) {
      const int c = (jt << 6) + wc + (j << 4) + lc;
      const float bias = sb1[c];
#pragma unroll
      for (int i = 0; i < 4; ++i) {
        const int rl = wr + (i << 4) + lr4;
#pragma unroll
        for (int q = 0; q < 4; ++q)
          hidden[((size_t)(row0 + rl + q) << 8) + c] = fmaxf(acc[i][j][q] + bias, 0.f);
      }
    }
    return;
  }

  // --- tconv ---
  float (*tb)[65] = (float(*)[65])smem;
  const int c = bid - 512;
  const int m = c >> 8;
  const int t2 = c & 255;
  const int c0 = (t2 & 15) << 6;
  const int r0 = (t2 >> 4) << 6;
  const size_t msz = (size_t)HD * HD;
  const float* src; u16* dst;
  if (m < 8)       { src = ew1 + (size_t)m * msz;       dst = ew1t + (size_t)m * msz; }
  else if (m < 16) { src = ew2 + (size_t)(m - 8) * msz; dst = ew2t + (size_t)(m - 8) * msz; }
  else if (m == 16){ src = uw1;                          dst = uw1t; }
  else             { src = uw2;                          dst = uw2t; }
  {
    const int lr = tid >> 2, q = (tid & 3) << 4;
    const float* s = src + (size_t)(r0 + lr) * HD + c0 + q;
#pragma unroll
    for (int j = 0; j < 16; j += 4) {
      const float4 v = *(const float4*)(s + j);
      tb[lr][q + j] = v.x; tb[lr][q + j + 1] = v.y;
      tb[lr][q + j + 2] = v.z; tb[lr][q + j + 3] = v.w;
    }
  }
  __syncthreads();
  {
    const int lc = tid >> 2, rq = (tid & 3) << 4;
    u16x8 o0, o1;
#pragma unroll
    for (int j = 0; j < 8; ++j) o0[j] = f2bf(tb[rq + j][lc]);
#pragma unroll
    for (int j = 0; j < 8; ++j) o1[j] = f2bf(tb[rq + 8 + j][lc]);
    u16* d = dst + (size_t)(c0 + lc) * HD + r0 + rq;
    *(u16x8*)d = o0;
    *(u16x8*)(d + 8) = o1;
  }
}

// ---------------- Logits: 128 tok/block, LDS histogram (r15), fused scan ----------------
__global__ __launch_bounds__(256) void logits_kernel(
    const float* __restrict__ hidden, const float* __restrict__ sw2,
    const float* __restrict__ sb2, int* __restrict__ routes, int* meta) {
  __shared__ float logl[32][8];
  __shared__ int lhist[NE];
  const int tid = threadIdx.x;
  if (tid < NE) lhist[tid] = 0;
  const int tok0 = blockIdx.x << 7;     // 128 tokens per block
  const int tl = tid >> 3, e2 = tid & 7;
  __syncthreads();
#pragma unroll 1
  for (int g4 = 0; g4 < 4; ++g4) {
    const float* hp = hidden + ((size_t)(tok0 + (g4 << 5) + tl) << 8);
    float a0 = 0.f, a1 = 0.f, a2 = 0.f, a3 = 0.f;
    for (int q = 0; q < SD; q += 8) {
      const float4 h0 = *(const float4*)&hp[q];
      const float4 h1 = *(const float4*)&hp[q + 4];
      a0 = fmaf(h0.x, sw2[((q + 0) << 3) + e2], a0);
      a1 = fmaf(h0.y, sw2[((q + 1) << 3) + e2], a1);
      a2 = fmaf(h0.z, sw2[((q + 2) << 3) + e2], a2);
      a3 = fmaf(h0.w, sw2[((q + 3) << 3) + e2], a3);
      a0 = fmaf(h1.x, sw2[((q + 4) << 3) + e2], a0);
      a1 = fmaf(h1.y, sw2[((q + 5) << 3) + e2], a1);
      a2 = fmaf(h1.z, sw2[((q + 6) << 3) + e2], a2);
      a3 = fmaf(h1.w, sw2[((q + 7) << 3) + e2], a3);
    }
    logl[tl][e2] = (a0 + a1) + (a2 + a3) + sb2[e2];
    __syncthreads();
    if (tid < 32) {
      float best = logl[tid][0]; int be = 0;
#pragma unroll
      for (int e = 1; e < 8; ++e) {
        const float v = logl[tid][e];
        if (v > best) { best = v; be = e; }
      }
      routes[tok0 + (g4 << 5) + tid] = be;
      atomicAdd(&lhist[be], 1);
    }
    __syncthreads();
  }
  if (tid < NE) atomicAdd(&meta[tid], lhist[tid]);
  __syncthreads();
  if (tid == 0) {
    __threadfence();
    const int done = atomicAdd(&meta[26], 1);
    if (done == (int)gridDim.x - 1) {
      int cnt[NE];
#pragma unroll
      for (int e = 0; e < NE; ++e) cnt[e] = atomicAdd(&meta[e], 0);
      int off = 0;
      for (int e = 0; e < NE; ++e) { meta[16 + e] = off; off += cnt[e]; }
      meta[24] = off;
      int nt = 0;
      for (int e = 0; e < NE; ++e) {
        const int s = meta[16 + e], en = meta[16 + e + 1];
        for (int r0 = s; r0 < en; r0 += 128) {
          meta[32 + nt] = e; meta[192 + nt] = r0; meta[352 + nt] = en; ++nt;
        }
      }
      meta[25] = nt;
      __threadfence();
    }
  }
}

// ---- perm (blocks 0..63, two-level counting r13) + xcvt rows 0..8959 (blocks 64..4543) ----
__global__ __launch_bounds__(256) void permx_kernel(
    const int* __restrict__ routes, int* meta, int* __restrict__ perm,
    const float* __restrict__ x, u16* __restrict__ xg) {
  const int bid = blockIdx.x;
  const int tid = threadIdx.x;
  if (bid >= 64) {
    // hidden32 (xg rows 0..8191) and bP (rows 8192..8959) are dead now
    xcvt_rows(x, xg, 0, bid - 64, tid);
    return;
  }
  __shared__ int lcnt[NE], lbase[NE], lcur[NE];
  if (tid < NE) { lcnt[tid] = 0; lcur[tid] = 0; }
  __syncthreads();
  const int b = bid * 256 + tid;
  const int r = routes[b];
  atomicAdd(&lcnt[r], 1);
  __syncthreads();
  if (tid < NE)
    lbase[tid] = meta[16 + tid] + atomicAdd(&meta[8 + tid], lcnt[tid]);
  __syncthreads();
  const int rank = atomicAdd(&lcur[r], 1);
  perm[lbase[r] + rank] = b;
}

// ---------------- GEMM1: hid[p] = relu(xg[perm[p]] @ [ew1[e] | uw1] + bias) ----------------
__global__ __launch_bounds__(256) void gemm1_kernel(
    const u16* __restrict__ xg, const u16* __restrict__ ew1t,
    const u16* __restrict__ uw1t, const float* __restrict__ eb1,
    const float* __restrict__ ub1, const int* __restrict__ meta,
    const int* __restrict__ perm, u16* __restrict__ hid) {
  const int nt = meta[25];
  // XCD-chunked, mt-major: grid 2160 = 16 jt x 135 mt
  const int pb = blockIdx.x;
  const int L = (pb & 7) * 270 + (pb >> 3);
  const int mt = L >> 4;
  const int jt = L & 15;
  if (mt >= nt) return;
  const int e = meta[32 + mt], row0 = meta[192 + mt], gend = meta[352 + mt];
  const u16* wbase = (jt < 8)
      ? ew1t + ((size_t)e << 20) + ((size_t)(jt << 7) << 10)
      : uw1t + ((size_t)((jt - 8) << 7) << 10);

  // 32KB unified LDS: K-loop sA/sB; epilogue reuses as [128][128] u16 tile.
  __shared__ u16 smem[16384];
  u16 (*sA)[4096] = (u16(*)[4096])smem;
  u16 (*sB)[4096] = (u16(*)[4096])(smem + 8192);

  const int tid = threadIdx.x;
  const int lane = tid & 63;
  const int wave = tid >> 6;
  const int wr = (wave >> 1) << 6;
  const int wc = (wave & 1) << 6;

  const int smrow = tid >> 2;
  const int skoff = (((tid & 3) ^ ((tid >> 3) & 3)) << 3);
  // A rows indirect through perm (token-order xg); clamp tail rows (stores
  // are gend-masked, clamped rows only feed junk compute)
  int rr0 = row0 + smrow;       if (rr0 > NTOK - 1) rr0 = NTOK - 1;
  int rr1 = row0 + smrow + 64;  if (rr1 > NTOK - 1) rr1 = NTOK - 1;
  const u16* ap0 = xg + (((size_t)perm[rr0]) << 10) + skoff;
  const u16* ap1 = xg + (((size_t)perm[rr1]) << 10) + skoff;
  const u16* bp0 = wbase + (((size_t)smrow) << 10) + skoff;
  const u16* bp1 = wbase + (((size_t)(smrow + 64)) << 10) + skoff;
  const int ldsoff = wave << 10;

  f32x4 acc[4][4];
#pragma unroll
  for (int i = 0; i < 4; ++i)
#pragma unroll
    for (int j = 0; j < 4; ++j) acc[i][j] = (f32x4){0.f, 0.f, 0.f, 0.f};

  gload16(ap0, (char*)sA[0] + ldsoff);
  gload16(ap1, (char*)sA[0] + 4096 + ldsoff);
  gload16(bp0, (char*)sB[0] + ldsoff);
  gload16(bp1, (char*)sB[0] + 4096 + ldsoff);

  const int sl = (((lane >> 4) ^ ((lane >> 1) & 3)) << 3);
  const int afrag = (wr + (lane & 15)) * 32 + sl;
  const int bfrag = (wc + (lane & 15)) * 32 + sl;

#pragma unroll
  for (int ks = 0; ks < 32; ++ks) {
    const int buf = ks & 1;
    __syncthreads();
    if (ks + 1 < 32) {
      const int k1 = (ks + 1) << 5;
      gload16(ap0 + k1, (char*)sA[buf ^ 1] + ldsoff);
      gload16(ap1 + k1, (char*)sA[buf ^ 1] + 4096 + ldsoff);
      gload16(bp0 + k1, (char*)sB[buf ^ 1] + ldsoff);
      gload16(bp1 + k1, (char*)sB[buf ^ 1] + 4096 + ldsoff);
    }
    bf16x8 av[4], bv[4];
#pragma unroll
    for (int f = 0; f < 4; ++f) {
      av[f] = *(const bf16x8*)&sA[buf][afrag + f * 512];
      bv[f] = *(const bf16x8*)&sB[buf][bfrag + f * 512];
    }
#pragma unroll
    for (int i = 0; i < 4; ++i)
#pragma unroll
      for (int j = 0; j < 4; ++j)
        acc[i][j] = __builtin_amdgcn_mfma_f32_16x16x32_bf16(av[i], bv[j], acc[i][j], 0, 0, 0);
  }

  // --- epilogue: bias+relu+cvt -> LDS tile, then 256B-contiguous stores ---
  __syncthreads();
  {
    const int lc = lane & 15;
    const int lr4 = (lane >> 4) << 2;
#pragma unroll
    for (int j = 0; j < 4; ++j) {
      const int c = wc + (j << 4) + lc;           // local col 0..127
      const int gc = (jt << 7) + c;
      const float bias = (gc < 1024) ? eb1[(e << 10) + gc] : ub1[gc - 1024];
#pragma unroll
      for (int i = 0; i < 4; ++i) {
        const int rl = wr + (i << 4) + lr4;
#pragma unroll
        for (int q = 0; q < 4; ++q)
          smem[(rl + q) * 128 + c] = f2bf(fmaxf(acc[i][j][q] + bias, 0.f));
      }
    }
  }
  __syncthreads();
  {
    const int l16 = lane & 15, rg = lane >> 4;
#pragma unroll
    for (int it = 0; it < 8; ++it) {
      const int lr = (wave << 5) + (it << 2) + rg;   // local row 0..127
      const int p = row0 + lr;
      const u16x8 v = *(const u16x8*)&smem[lr * 128 + (l16 << 3)];
      if (p < gend)
        *(u16x8*)&hid[((size_t)p << 11) + (jt << 7) + (l16 << 3)] = v;
    }
  }
}

// ---------------- GEMM2: out[perm[p]][c] = hid[p] @ [ew2[e]; uw2] + eb2[e] + ub2 ----------------
__global__ __launch_bounds__(256) void gemm2_kernel(
    const u16* __restrict__ hid, const u16* __restrict__ ew2t,
    const u16* __restrict__ uw2t, const float* __restrict__ eb2,
    const float* __restrict__ ub2, const int* __restrict__ meta,
    const int* __restrict__ perm, float* __restrict__ out) {
  const int nt = meta[25];
  // XCD-chunked, mt-major: grid 1080 = 8 jt x 135 mt
  const int pb = blockIdx.x;
  const int L = (pb & 7) * 135 + (pb >> 3);
  const int mt = L >> 3;
  const int jt = L & 7;
  if (mt >= nt) return;
  const int e = meta[32 + mt], row0 = meta[192 + mt], gend = meta[352 + mt];
  const int n0 = jt << 7;

  // 32KB unified LDS: K-loop sA/sB; epilogue reuses as [64][128] f32 half-tile.
  __shared__ u16 smem[16384];
  u16 (*sA)[4096] = (u16(*)[4096])smem;
  u16 (*sB)[4096] = (u16(*)[4096])(smem + 8192);
  float* smemf = (float*)smem;

  const int tid = threadIdx.x;
  const int lane = tid & 63;
  const int wave = tid >> 6;
  const int wr = (wave >> 1) << 6;
  const int wc = (wave & 1) << 6;

  const int smrow = tid >> 2;
  const int skoff = (((tid & 3) ^ ((tid >> 3) & 3)) << 3);
  const u16* ap0 = hid + (((size_t)(row0 + smrow)) << 11) + skoff;
  const u16* ap1 = hid + (((size_t)(row0 + smrow + 64)) << 11) + skoff;
  const u16* ebase = ew2t + ((size_t)e << 20);
  const size_t brow0 = (((size_t)(n0 + smrow)) << 10) + skoff;
  const size_t brow1 = (((size_t)(n0 + smrow + 64)) << 10) + skoff;
  const int ldsoff = wave << 10;

  f32x4 acc[4][4];
#pragma unroll
  for (int i = 0; i < 4; ++i)
#pragma unroll
    for (int j = 0; j < 4; ++j) acc[i][j] = (f32x4){0.f, 0.f, 0.f, 0.f};

  gload16(ap0, (char*)sA[0] + ldsoff);
  gload16(ap1, (char*)sA[0] + 4096 + ldsoff);
  gload16(ebase + brow0, (char*)sB[0] + ldsoff);
  gload16(ebase + brow1, (char*)sB[0] + 4096 + ldsoff);

  const int sl = (((lane >> 4) ^ ((lane >> 1) & 3)) << 3);
  const int afrag = (wr + (lane & 15)) * 32 + sl;
  const int bfrag = (wc + (lane & 15)) * 32 + sl;

#pragma unroll
  for (int ks = 0; ks < 64; ++ks) {
    const int buf = ks & 1;
    __syncthreads();
    if (ks + 1 < 64) {
      const int k1 = (ks + 1) << 5;
      const u16* bb = (k1 < 1024) ? ebase : uw2t;
      const int kk = k1 & 1023;
      gload16(ap0 + k1, (char*)sA[buf ^ 1] + ldsoff);
      gload16(ap1 + k1, (char*)sA[buf ^ 1] + 4096 + ldsoff);
      gload16(bb + brow0 + kk, (char*)sB[buf ^ 1] + ldsoff);
      gload16(bb + brow1 + kk, (char*)sB[buf ^ 1] + 4096 + ldsoff);
    }
    bf16x8 av[4], bv[4];
#pragma unroll
    for (int f = 0; f < 4; ++f) {
      av[f] = *(const bf16x8*)&sA[buf][afrag + f * 512];
      bv[f] = *(const bf16x8*)&sB[buf][bfrag + f * 512];
    }
#pragma unroll
    for (int i = 0; i < 4; ++i)
#pragma unroll
      for (int j = 0; j < 4; ++j)
        acc[i][j] = __builtin_amdgcn_mfma_f32_16x16x32_bf16(av[i], bv[j], acc[i][j], 0, 0, 0);
  }

  // --- epilogue: 2 half-passes via [64][128] f32 LDS tile, 512B/row stores ---
  const int lc = lane & 15;
  const int lr4 = (lane >> 4) << 2;
  float b2v[4];
#pragma unroll
  for (int j = 0; j < 4; ++j) {
    const int c = n0 + wc + (j << 4) + lc;
    b2v[j] = eb2[(e << 10) + c] + ub2[c];
  }
  __syncthreads();
#pragma unroll
  for (int pass = 0; pass < 2; ++pass) {
    if ((wave >> 1) == pass) {
#pragma unroll
      for (int j = 0; j < 4; ++j) {
        const int c = wc + (j << 4) + lc;         // local col 0..127
#pragma unroll
        for (int i = 0; i < 4; ++i) {
          const int lrl = (i << 4) + lr4;          // local row 0..63
#pragma unroll
          for (int q = 0; q < 4; ++q)
            smemf[(lrl + q) * 128 + c] = acc[i][j][q] + b2v[j];
        }
      }
    }
    __syncthreads();
#pragma unroll
    for (int it = 0; it < 8; ++it) {
      const int lrl = (it << 3) + (wave << 1) + (lane >> 5);  // 0..63
      const int p = row0 + (pass << 6) + lrl;
      const float4 v = *(const float4*)&smemf[lrl * 128 + ((lane & 31) << 2)];
      if (p < gend)
        *(float4*)&out[((size_t)perm[p] << 10) + n0 + ((lane & 31) << 2)] = v;
    }
    __syncthreads();
  }
}

extern "C" void kernel_launch(void* const* d_in, const int* in_sizes, int n_in,
                              void* d_out, int out_size, void* d_ws, size_t ws_size,
                              hipStream_t stream) {
  const float* x   = (const float*)d_in[0];
  const float* ue  = (const float*)d_in[1];
  const float* sw1 = (const float*)d_in[2];
  const float* sb1 = (const float*)d_in[3];
  const float* sw2 = (const float*)d_in[4];
  const float* sb2 = (const float*)d_in[5];
  const float* ew1 = (const float*)d_in[6];
  const float* eb1 = (const float*)d_in[7];
  const float* ew2 = (const float*)d_in[8];
  const float* eb2 = (const float*)d_in[9];
  const float* uw1 = (const float*)d_in[10];
  const float* ub1 = (const float*)d_in[11];
  const float* uw2 = (const float*)d_in[12];
  const float* ub2 = (const float*)d_in[13];
  float* out = (float*)d_out;

  char* w = (char*)d_ws;
  int* meta = (int*)w;    w += 4096;
  int* routes = (int*)w;  w += NTOK * 4;
  int* perm = (int*)w;    w += NTOK * 4;
  char* region = w;
  u16* xg   = (u16*)region;                                             // 33,816,576 B
  u16* ew1t = (u16*)(region + 33816576ull);                             // 16 MiB
  u16* ew2t = (u16*)(region + 33816576ull + 16777216ull);               // 16 MiB
  u16* uw1t = (u16*)(region + 33816576ull + 2 * 16777216ull);           // 2 MiB
  u16* uw2t = (u16*)(region + 33816576ull + 2 * 16777216ull + 2097152ull);
  u16* hid  = (u16*)(region + 33816576ull + 2 * 16777216ull + 2 * 2097152ull);  // 67,633,152 B
  const size_t region_sz = 33816576ull + 2 * 16777216ull + 2 * 2097152ull + 67633152ull;
  // router-phase aliases: hidden32 = xg rows 0..8191; bP = xg rows 8192..8959;
  // aP in the (dead-until-gemm1) hid region. rtconv's xcvt only touches xg
  // rows >= 8960; rows < 8960 convert in permx (hidden32/bP dead there).
  _Float16* aP     = (_Float16*)(region + 33816576ull + 2 * 16777216ull + 2 * 2097152ull);
  float* hidden32  = (float*)region;
  _Float16* bP     = (_Float16*)(region + 16777216ull);
  if (135168ull + region_sz > ws_size) return;

  hipMemsetAsync(meta, 0, 4096, stream);
  prep_kernel<<<8256, 256, 0, stream>>>(ue, aP, sw1, bP);
  rtconv_kernel<<<8832, 256, 0, stream>>>(aP, bP, sb1, hidden32,
                                          ew1, ew2, uw1, uw2,
                                          ew1t, ew2t, uw1t, uw2t, x, xg);
  logits_kernel<<<NTOK / 128, 256, 0, stream>>>(hidden32, sw2, sb2, routes, meta);
  permx_kernel<<<64 + 4480, 256, 0, stream>>>(routes, meta, perm, x, xg);
  gemm1_kernel<<<2160, 256, 0, stream>>>(xg, ew1t, uw1t, eb1, ub1, meta, perm, hid);
  gemm2_kernel<<<1080, 256, 0, stream>>>(hid, ew2t, uw2t, eb2, ub2, meta, perm, out);
}